// Round 4
// baseline (430.177 us; speedup 1.0000x reference)
//
#include <hip/hip_runtime.h>
#include <cstdint>
#include <cstddef>

// ---------------------------------------------------------------------------
// FCAGAT: 3x GATConv (H=2, C=64) + ELU + concat + MLP(384->128->1)
// R8: scatter_p LDS radix-partition (was 92.7us scatter_b, 8x write amp).
// R9: split-K 2 final_mlp + mlp_tail. Occupancy theory WRONG: VALUBusy stuck
// ~49% -> kernel is LDS-pipe-bound: 3 ds_read_b128 per 32 fma = 4 SIMDs
// demand 144 LDS cyc per 64 VALU cyc (2.25x oversub) -> VALUBusy 44% predicted
// = 45-50% measured. R10: 8x8 register blocking (128x128 tile, TKK=16):
// 4 ds_read_b128 per 64 fma (1.5x better ratio) + bank-clean layout
// (A-reads broadcast, B float4 swizzle j^(j>>3) bijective 2-way, A-writes
// 2-way => all free per m136). Expect ~35-40us, VALUBusy 60-70%, conflicts <1M.
//   K1 zeroB      : bktCnt = 0   (one counter per 64B line)
//   K2 scatter_p  : LDS-partitioned edge scatter -> (bucket,slice) runs
//   K3 sortbkt    : read 8 slices, LDS counting sort by dLow + self-loop inj
//   K4 gemm_att   : xw = x@W tiled GEMM (swizzled LDS) + fused att dots
//   K5 aggregate  : wave/node: lane-parallel online softmax + gather
//   K6 final_mlp_part : split-K 8x8-blocked GEMM elu(agg+b)@Wc1 -> 2 partials
//   K7 mlp_tail   : out = relu(p0+p1+bc1)@Wc2 + bc2, wave/row
// ---------------------------------------------------------------------------

__device__ __forceinline__ float lrelu02(float x) { return x > 0.f ? x : 0.2f * x; }
__device__ __forceinline__ float elu1(float x) { return x > 0.f ? x : (__expf(x) - 1.f); }

#define TM 64
#define TN 128
#define TKK 32
#define SLICES 8
#define CAPX 448               // per-(bucket,slice): mean ~240, +13 sigma
#define BCAP (SLICES * CAPX)   // 3584 >= max bucket total (~2046)

#define SBS 512                // scatter block threads
#define SEPT 16                // edges per thread
#define STB (SBS * SEPT)       // 8192 edges per block
#define NBINS_PAD 1024         // >= 3*nbpc = 939, padded pow2

#define FTM 128                // final_mlp M-tile
#define FTKK 16                // final_mlp K-tile

// ---------------- K4: XW = X[M,K] @ W[K,128] + fused attention dots ----------
__global__ __launch_bounds__(256) void gemm_att(
    const float* __restrict__ X, const float* __restrict__ W,
    const float* __restrict__ att_s, const float* __restrict__ att_d,
    float* __restrict__ XW, float* __restrict__ a_src, float* __restrict__ a_dst,
    int M, int K) {
  __shared__ __align__(16) float xs[TKK][TM];     // 8 KB, swizzled transposed A
  __shared__ __align__(16) float4 wsB[TKK][TN/4]; // 16 KB, swizzled B
  const int tid = threadIdx.x;
  const int tx = tid & 15;
  const int ty = tid >> 4;
  const int row0 = blockIdx.x * TM;
  float acc[4][8];
#pragma unroll
  for (int r = 0; r < 4; ++r)
#pragma unroll
    for (int c = 0; c < 8; ++c) acc[r][c] = 0.f;

  const int lr = tid >> 2;
  const int lk = (tid & 3) * 8;
  const int wr = tid >> 3;
  const int bb = (tid & 7) * 4;
  const int xcol = lr ^ (((lk >> 3) & 1) * 16);
  const int p0 = (tx * 2) ^ (2 * ((tx * 2) >> 3));
  const int p1 = (tx * 2 + 1) ^ (2 * ((tx * 2 + 1) >> 3));

  for (int k0 = 0; k0 < K; k0 += TKK) {
    int xrow = row0 + lr; if (xrow >= M) xrow = M - 1;
    const float4* xp = (const float4*)(X + (size_t)xrow * K + k0 + lk);
    float4 xa = xp[0];
    float4 xb = xp[1];
    const float4* wp = (const float4*)(W + (size_t)(k0 + wr) * TN + bb * 4);
    float4 w0 = wp[0], w1 = wp[1], w2 = wp[2], w3 = wp[3];
    __syncthreads();
    xs[lk + 0][xcol] = xa.x; xs[lk + 1][xcol] = xa.y;
    xs[lk + 2][xcol] = xa.z; xs[lk + 3][xcol] = xa.w;
    xs[lk + 4][xcol] = xb.x; xs[lk + 5][xcol] = xb.y;
    xs[lk + 6][xcol] = xb.z; xs[lk + 7][xcol] = xb.w;
    {
      int b0i = bb + 0; wsB[wr][b0i ^ (2 * (b0i >> 3))] = w0;
      int b1i = bb + 1; wsB[wr][b1i ^ (2 * (b1i >> 3))] = w1;
      int b2i = bb + 2; wsB[wr][b2i ^ (2 * (b2i >> 3))] = w2;
      int b3i = bb + 3; wsB[wr][b3i ^ (2 * (b3i >> 3))] = w3;
    }
    __syncthreads();
#pragma unroll
    for (int k = 0; k < TKK; ++k) {
      const int acol = (ty * 4) ^ (((k >> 3) & 1) * 16);
      float4 a = *(const float4*)&xs[k][acol];
      float4 b0 = wsB[k][p0];
      float4 b1 = wsB[k][p1];
      float av[4] = {a.x, a.y, a.z, a.w};
      float bv[8] = {b0.x, b0.y, b0.z, b0.w, b1.x, b1.y, b1.z, b1.w};
#pragma unroll
      for (int r = 0; r < 4; ++r)
#pragma unroll
        for (int c = 0; c < 8; ++c)
          acc[r][c] = fmaf(av[r], bv[c], acc[r][c]);
    }
  }
#pragma unroll
  for (int r = 0; r < 4; ++r) {
    int row = row0 + ty * 4 + r;
    if (row < M) {
      float4 o0 = {acc[r][0], acc[r][1], acc[r][2], acc[r][3]};
      float4 o1 = {acc[r][4], acc[r][5], acc[r][6], acc[r][7]};
      float4* op = (float4*)(XW + (size_t)row * TN + tx * 8);
      op[0] = o0; op[1] = o1;
    }
  }
  // fused attention dots: this thread's 8 cols all belong to head tx>>3
  float ps[4] = {0.f, 0.f, 0.f, 0.f}, pd[4] = {0.f, 0.f, 0.f, 0.f};
#pragma unroll
  for (int c = 0; c < 8; ++c) {
    float as = att_s[tx * 8 + c], ad = att_d[tx * 8 + c];
#pragma unroll
    for (int r = 0; r < 4; ++r) {
      ps[r] = fmaf(acc[r][c], as, ps[r]);
      pd[r] = fmaf(acc[r][c], ad, pd[r]);
    }
  }
#pragma unroll
  for (int off = 1; off < 8; off <<= 1) {
#pragma unroll
    for (int r = 0; r < 4; ++r) {
      ps[r] += __shfl_xor(ps[r], off);
      pd[r] += __shfl_xor(pd[r], off);
    }
  }
  if ((tx & 7) == 0) {
    int head = tx >> 3;
#pragma unroll
    for (int r = 0; r < 4; ++r) {
      int row = row0 + ty * 4 + r;
      if (row < M) {
        a_src[row * 2 + head] = ps[r];
        a_dst[row * 2 + head] = pd[r];
      }
    }
  }
}

// ---------------- K1: zero (line-padded) bucket counters ----------------
__global__ void zeroB(int* __restrict__ a, int n) {
  int i = blockIdx.x * blockDim.x + threadIdx.x;
  if (i < n) a[i] = 0;
}

// ---------------- K2: LDS radix-partition edge scatter ----------------
__global__ __launch_bounds__(512) void scatter_p(
    const int* __restrict__ ei0, const int* __restrict__ ei1,
    const int* __restrict__ ei2, int E0, int E1, int E2,
    int nbpc, int* __restrict__ bktCnt, int* __restrict__ bkt) {
  __shared__ int hist[NBINS_PAD];
  __shared__ int binStart[NBINS_PAD];
  __shared__ int binResv[NBINS_PAD];
  __shared__ int fillB[NBINS_PAD];
  __shared__ int scanBuf[SBS];
  __shared__ int stage[STB];
  __shared__ int gdst[STB];
  const int tid = threadIdx.x;
  const int slice = blockIdx.x & (SLICES - 1);   // ~= XCD id (round-robin)
  const int nbins = 3 * nbpc;
  const int c1 = E0, c2 = E0 + E1, totE = c2 + E2;
  const int eb = blockIdx.x * STB;

  for (int b = tid; b < NBINS_PAD; b += SBS) hist[b] = 0;
  __syncthreads();

  // load 16 edges/thread, histogram bins
  int binv[SEPT], payv[SEPT];
#pragma unroll
  for (int k = 0; k < SEPT; ++k) {
    int g = eb + k * SBS + tid;
    int bn = -1, pay = 0;
    if (g < totE) {
      int s, d, cat;
      if (g < c1)      { s = ei0[g]; d = ei0[E0 + g]; cat = 0; }
      else if (g < c2) { int t = g - c1; s = ei1[t]; d = ei1[E1 + t]; cat = 1; }
      else             { int t = g - c2; s = ei2[t]; d = ei2[E2 + t]; cat = 2; }
      bn = cat * nbpc + (d >> 7);
      pay = ((d & 127) << 16) | s;
      atomicAdd(&hist[bn], 1);
    }
    binv[k] = bn; payv[k] = pay;
  }
  __syncthreads();

  // exclusive scan of hist -> binStart (2 bins/thread, Hillis-Steele on 512)
  const int a0 = hist[tid * 2], a1 = hist[tid * 2 + 1];
  scanBuf[tid] = a0 + a1;
  __syncthreads();
  for (int off = 1; off < SBS; off <<= 1) {
    int v = (tid >= off) ? scanBuf[tid - off] : 0;
    __syncthreads();
    scanBuf[tid] += v;
    __syncthreads();
  }
  const int total = scanBuf[SBS - 1];
  const int base = (tid > 0) ? scanBuf[tid - 1] : 0;
  binStart[tid * 2] = base;
  binStart[tid * 2 + 1] = base + a0;

  // reserve a contiguous run per non-empty bin (XCD-private slice counters)
  for (int b = tid; b < NBINS_PAD; b += SBS) {
    fillB[b] = 0;
    int c = hist[b];
    if (c > 0 && b < nbins)
      binResv[b] = atomicAdd(&bktCnt[(b * SLICES + slice) * 16], c);
  }
  __syncthreads();

  // counting-sort edges into LDS stage, record global destination
#pragma unroll
  for (int k = 0; k < SEPT; ++k) {
    int bn = binv[k];
    if (bn >= 0) {
      int f = atomicAdd(&fillB[bn], 1);
      int p = binStart[bn] + f;
      int go = binResv[bn] + f;
      stage[p] = payv[k];
      gdst[p] = (go < CAPX) ? ((bn * SLICES + slice) * CAPX + go) : -1;
    }
  }
  __syncthreads();

  // run-ordered write-out: consecutive lanes -> consecutive addresses
  for (int i = tid; i < total; i += SBS) {
    int g = gdst[i];
    if (g >= 0) bkt[g] = stage[i];
  }
}

// ---------------- K3: merge slices, LDS counting sort, compact in place -----
// Self-loops injected analytically: cntA init = 1, self-loop src at slot
// scanA[t]-1 (edges fill relative slots 0..cntA-2 via fillA).
__global__ __launch_bounds__(256) void sortbkt(
    int* __restrict__ bkt, const int* __restrict__ bktCnt,
    int2* __restrict__ offcnt, int Nn, int nbpc) {
  __shared__ int cntA[128], scanA[128], fillA[128];
  __shared__ int esort[BCAP];
  const int tid = threadIdx.x;
  const int b = blockIdx.x;
  const int cat = b / nbpc, bl = b - cat * nbpc, dBase = bl << 7;
  if (tid < 128) {
    cntA[tid] = (dBase + tid < Nn) ? 1 : 0;   // self-loop
    fillA[tid] = 0;
  }
  __syncthreads();
  int ns[SLICES];
#pragma unroll
  for (int s = 0; s < SLICES; ++s)
    ns[s] = min(bktCnt[(b * SLICES + s) * 16], CAPX);
  // pass 1: histogram by dLow
#pragma unroll
  for (int s = 0; s < SLICES; ++s) {
    const int* seg = bkt + (size_t)(b * SLICES + s) * CAPX;
    for (int i = tid; i < ns[s]; i += 256) atomicAdd(&cntA[seg[i] >> 16], 1);
  }
  __syncthreads();
  if (tid < 128) scanA[tid] = cntA[tid];
  __syncthreads();
  for (int off = 1; off < 128; off <<= 1) {
    int t = (tid < 128 && tid >= off) ? scanA[tid - off] : 0;
    __syncthreads();
    if (tid < 128) scanA[tid] += t;
    __syncthreads();
  }
  // pass 2: place edges (exclusive start for node t = scanA[t]-cntA[t])
#pragma unroll
  for (int s = 0; s < SLICES; ++s) {
    const int* seg = bkt + (size_t)(b * SLICES + s) * CAPX;
    for (int i = tid; i < ns[s]; i += 256) {
      int v = seg[i];
      int n = v >> 16;
      int p = scanA[n] - cntA[n] + atomicAdd(&fillA[n], 1);
      esort[p] = v & 0xFFFF;
    }
  }
  // self-loop: last slot of node's segment
  if (tid < 128 && dBase + tid < Nn) esort[scanA[tid] - 1] = dBase + tid;
  __syncthreads();
  const int tot = scanA[127];
  int* outp = bkt + (size_t)b * BCAP;     // compact to bucket base
  for (int i = tid; i < tot; i += 256) outp[i] = esort[i];
  if (tid < 128 && dBase + tid < Nn)
    offcnt[(size_t)cat * Nn + dBase + tid] =
        make_int2(b * BCAP + scanA[tid] - cntA[tid], cntA[tid]);
}

// ---------------- K5: lane-parallel segment softmax + gather ----------------
__global__ __launch_bounds__(256) void aggregate(
    const float* __restrict__ xw, const float* __restrict__ a_src,
    const float* __restrict__ a_dst, const int2* __restrict__ offcnt,
    const int* __restrict__ adjS, float* __restrict__ agg, int Nn) {
  const int node = (int)((blockIdx.x * (size_t)blockDim.x + threadIdx.x) >> 6);
  const int lane = threadIdx.x & 63;
  if (node >= Nn) return;
  const int2 oc = offcnt[node];
  const int base = oc.x, end = oc.x + oc.y;
  const float2 ad = ((const float2*)a_dst)[node];

  // phase 1: lane-strided online softmax stats; keep first chunk in regs
  float m0 = -1e30f, s0 = 0.f, m1 = -1e30f, s1 = 0.f;
  int sv0 = 0; float ex0 = -1e30f, ey0 = -1e30f;
  for (int cb = base; cb < end; cb += 64) {
    int j = cb + lane;
    int sv = 0; float ex = -1e30f, ey = -1e30f;
    if (j < end) {
      sv = adjS[j];
      float2 as = ((const float2*)a_src)[sv];
      ex = lrelu02(as.x + ad.x);
      ey = lrelu02(as.y + ad.y);
      float nm0 = fmaxf(m0, ex);
      s0 = s0 * __expf(m0 - nm0) + __expf(ex - nm0); m0 = nm0;
      float nm1 = fmaxf(m1, ey);
      s1 = s1 * __expf(m1 - nm1) + __expf(ey - nm1); m1 = nm1;
    }
    if (cb == base) { sv0 = sv; ex0 = ex; ey0 = ey; }
  }
#pragma unroll
  for (int off = 32; off; off >>= 1) {
    float om0 = __shfl_xor(m0, off), os0 = __shfl_xor(s0, off);
    float nm0 = fmaxf(m0, om0);
    s0 = s0 * __expf(m0 - nm0) + os0 * __expf(om0 - nm0); m0 = nm0;
    float om1 = __shfl_xor(m1, off), os1 = __shfl_xor(s1, off);
    float nm1 = fmaxf(m1, om1);
    s1 = s1 * __expf(m1 - nm1) + os1 * __expf(om1 - nm1); m1 = nm1;
  }
  const float inv0 = 1.f / s0, inv1 = 1.f / s1;

  // phase 2: weight once per edge (its lane), shfl-broadcast, gather x4
  float acc0 = 0.f, acc1 = 0.f;
  for (int cb = base; cb < end; cb += 64) {
    const int cnt = min(64, end - cb);
    int srcv; float w0v, w1v;
    if (cb == base) {
      srcv = sv0;
      w0v = __expf(ex0 - m0) * inv0;   // inactive lanes: exp(-inf)=0
      w1v = __expf(ey0 - m1) * inv1;
    } else {
      srcv = 0; float ex = -1e30f, ey = -1e30f;
      if (lane < cnt) {
        srcv = adjS[cb + lane];
        float2 as = ((const float2*)a_src)[srcv];
        ex = lrelu02(as.x + ad.x);
        ey = lrelu02(as.y + ad.y);
      }
      w0v = __expf(ex - m0) * inv0;
      w1v = __expf(ey - m1) * inv1;
    }
    int k = 0;
    for (; k + 4 <= cnt; k += 4) {
      int sa = __shfl(srcv, k),     sb = __shfl(srcv, k + 1);
      int sc = __shfl(srcv, k + 2), sd = __shfl(srcv, k + 3);
      float wa0 = __shfl(w0v, k),     wb0 = __shfl(w0v, k + 1);
      float wc0 = __shfl(w0v, k + 2), wd0 = __shfl(w0v, k + 3);
      float wa1 = __shfl(w1v, k),     wb1 = __shfl(w1v, k + 1);
      float wc1 = __shfl(w1v, k + 2), wd1 = __shfl(w1v, k + 3);
      const float* pa = xw + (size_t)sa * 128 + lane;
      const float* pb = xw + (size_t)sb * 128 + lane;
      const float* pc = xw + (size_t)sc * 128 + lane;
      const float* pd = xw + (size_t)sd * 128 + lane;
      float xa0 = pa[0], xa1 = pa[64];
      float xb0 = pb[0], xb1 = pb[64];
      float xc0 = pc[0], xc1 = pc[64];
      float xd0 = pd[0], xd1 = pd[64];
      acc0 = fmaf(wa0, xa0, acc0); acc1 = fmaf(wa1, xa1, acc1);
      acc0 = fmaf(wb0, xb0, acc0); acc1 = fmaf(wb1, xb1, acc1);
      acc0 = fmaf(wc0, xc0, acc0); acc1 = fmaf(wc1, xc1, acc1);
      acc0 = fmaf(wd0, xd0, acc0); acc1 = fmaf(wd1, xd1, acc1);
    }
    for (; k < cnt; ++k) {
      int s = __shfl(srcv, k);
      float w0 = __shfl(w0v, k);
      float w1 = __shfl(w1v, k);
      const float* p = xw + (size_t)s * 128 + lane;
      acc0 = fmaf(w0, p[0], acc0);
      acc1 = fmaf(w1, p[64], acc1);
    }
  }
  agg[(size_t)node * 128 + lane] = acc0;
  agg[(size_t)node * 128 + 64 + lane] = acc1;
}

// ---------------- K6: split-K 8x8-blocked MLP GEMM, partials to ws ----------
// 128x128 tile, 256 threads (16x16, each 8x8 outputs), TKK=16.
// Per k: 4 ds_read_b128 -> 64 fma (vs old 3 -> 32). Bank-clean:
// A-reads 4-address broadcast, B swizzle P(j)=j^(j>>3) bijective 2-way,
// A-writes 2-way (free per m136).
__global__ __launch_bounds__(256) void final_mlp_part(
    const float* __restrict__ agg0, const float* __restrict__ agg1,
    const float* __restrict__ agg2, const float* __restrict__ bias0,
    const float* __restrict__ bias1, const float* __restrict__ bias2,
    const float* __restrict__ Wc1, float* __restrict__ hid0,
    float* __restrict__ hid1, int Nn) {
  __shared__ __align__(16) float xs[FTKK][FTM];   // 8 KB, transposed A
  __shared__ __align__(16) float4 wsB4[FTKK][32]; // 8 KB, swizzled B
  const int tid = threadIdx.x;
  const int tx = tid & 15;        // col group (8 cols)
  const int ty = tid >> 4;        // row group (8 rows)
  const int row0 = blockIdx.x * FTM;
  const int khalf = blockIdx.y;
  const int kbeg = khalf * 192, kend = kbeg + 192;
  float acc[8][8];
#pragma unroll
  for (int r = 0; r < 8; ++r)
#pragma unroll
    for (int c = 0; c < 8; ++c) acc[r][c] = 0.f;

  // staging ids
  const int sr = tid >> 1;                 // A row 0..127
  const int sk = (tid & 1) * 8;            // A k-offset 0 or 8
  const int wr = tid >> 4;                 // B k-row 0..15
  const int j0 = tx * 2, j1 = tx * 2 + 1;  // B float4 logical idx
  const int pj0 = j0 ^ (j0 >> 3);          // swizzled (bijective, 2-way free)
  const int pj1 = j1 ^ (j1 >> 3);

  int rowA = row0 + sr; if (rowA >= Nn) rowA = Nn - 1;

  float4 xa, xb, ba, bbv, w0, w1;
  // prefetch k-tile k0 into regs (elu deferred to LDS-write)
  {
    const int kg = kbeg + sk;
    const int sel = kg >> 7, q = kg & 127;
    const float* aggp = (sel == 0) ? agg0 : (sel == 1) ? agg1 : agg2;
    const float* bp   = (sel == 0) ? bias0 : (sel == 1) ? bias1 : bias2;
    xa = *(const float4*)(aggp + (size_t)rowA * 128 + q);
    xb = *(const float4*)(aggp + (size_t)rowA * 128 + q + 4);
    ba = *(const float4*)(bp + q);
    bbv = *(const float4*)(bp + q + 4);
    const float4* wp = (const float4*)(Wc1 + (size_t)(kbeg + wr) * 128);
    w0 = wp[j0]; w1 = wp[j1];
  }

  for (int k0 = kbeg; k0 < kend; k0 += FTKK) {
    __syncthreads();
    xs[sk + 0][sr] = elu1(xa.x + ba.x);
    xs[sk + 1][sr] = elu1(xa.y + ba.y);
    xs[sk + 2][sr] = elu1(xa.z + ba.z);
    xs[sk + 3][sr] = elu1(xa.w + ba.w);
    xs[sk + 4][sr] = elu1(xb.x + bbv.x);
    xs[sk + 5][sr] = elu1(xb.y + bbv.y);
    xs[sk + 6][sr] = elu1(xb.z + bbv.z);
    xs[sk + 7][sr] = elu1(xb.w + bbv.w);
    wsB4[wr][pj0] = w0;
    wsB4[wr][pj1] = w1;
    __syncthreads();
    if (k0 + FTKK < kend) {   // prefetch next tile: drains under compute
      const int kg = k0 + FTKK + sk;
      const int sel = kg >> 7, q = kg & 127;
      const float* aggp = (sel == 0) ? agg0 : (sel == 1) ? agg1 : agg2;
      const float* bp   = (sel == 0) ? bias0 : (sel == 1) ? bias1 : bias2;
      xa = *(const float4*)(aggp + (size_t)rowA * 128 + q);
      xb = *(const float4*)(aggp + (size_t)rowA * 128 + q + 4);
      ba = *(const float4*)(bp + q);
      bbv = *(const float4*)(bp + q + 4);
      const float4* wp = (const float4*)(Wc1 + (size_t)(k0 + FTKK + wr) * 128);
      w0 = wp[j0]; w1 = wp[j1];
    }
#pragma unroll
    for (int k = 0; k < FTKK; ++k) {
      const float4 a0 = *(const float4*)&xs[k][ty * 8];
      const float4 a1 = *(const float4*)&xs[k][ty * 8 + 4];
      const float4 b0 = wsB4[k][pj0];
      const float4 b1 = wsB4[k][pj1];
      const float av[8] = {a0.x, a0.y, a0.z, a0.w, a1.x, a1.y, a1.z, a1.w};
      const float bv[8] = {b0.x, b0.y, b0.z, b0.w, b1.x, b1.y, b1.z, b1.w};
#pragma unroll
      for (int r = 0; r < 8; ++r)
#pragma unroll
        for (int c = 0; c < 8; ++c)
          acc[r][c] = fmaf(av[r], bv[c], acc[r][c]);
    }
  }

  float* hp = khalf ? hid1 : hid0;
#pragma unroll
  for (int r = 0; r < 8; ++r) {
    int row = row0 + ty * 8 + r;
    if (row < Nn) {
      float4 o0 = {acc[r][0], acc[r][1], acc[r][2], acc[r][3]};
      float4 o1 = {acc[r][4], acc[r][5], acc[r][6], acc[r][7]};
      float4* op = (float4*)(hp + (size_t)row * 128 + tx * 8);
      op[0] = o0; op[1] = o1;
    }
  }
}

// ---------------- K7: out = relu(p0+p1+bc1)@Wc2 + bc2, wave per row --------
__global__ __launch_bounds__(256) void mlp_tail(
    const float* __restrict__ hid0, const float* __restrict__ hid1,
    const float* __restrict__ bc1, const float* __restrict__ Wc2,
    const float* __restrict__ bc2, float* __restrict__ out, int Nn) {
  const int lane = threadIdx.x & 63;
  const int row = blockIdx.x * 4 + (threadIdx.x >> 6);
  if (row >= Nn) return;
  const float b0 = bc1[lane], b1 = bc1[lane + 64];
  const float wa = Wc2[lane], wb = Wc2[lane + 64];
  const size_t o = (size_t)row * 128 + lane;
  float h0 = hid0[o] + hid1[o] + b0;
  float h1 = hid0[o + 64] + hid1[o + 64] + b1;
  float s = fmaxf(h0, 0.f) * wa + fmaxf(h1, 0.f) * wb;
#pragma unroll
  for (int off = 32; off; off >>= 1) s += __shfl_xor(s, off);
  if (lane == 0) out[row] = s + bc2[0];
}

// ---------------------------------------------------------------------------
extern "C" void kernel_launch(void* const* d_in, const int* in_sizes, int n_in,
                              void* d_out, int out_size, void* d_ws, size_t ws_size,
                              hipStream_t stream) {
  const int Nn = out_size;            // 40000
  const int E0 = in_sizes[1] / 2;
  const int E1 = in_sizes[7] / 2;
  const int E2 = in_sizes[13] / 2;
  const int totE = E0 + E1 + E2;
  const int Nt = 3 * Nn;
  const int nbpc = (Nn + 127) / 128;  // buckets per category (313)
  const int NB = 3 * nbpc;            // 939

  char* base = (char*)d_ws;
  size_t off = 0;
  auto carve = [&](size_t bytes) -> void* {
    off = (off + 255) & ~(size_t)255;
    void* p = base + off;
    off += bytes;
    return p;
  };
  float* xw     = (float*)carve((size_t)Nn * 128 * 4);      // reused: hidp0
  float* agg3   = (float*)carve((size_t)Nt * 128 * 4);
  float* a_src3 = (float*)carve((size_t)Nt * 2 * 4);
  float* a_dst3 = (float*)carve((size_t)Nt * 2 * 4);
  int*  bktCnt  = (int*)carve((size_t)NB * SLICES * 16 * 4); // line-padded
  int2* offcnt3 = (int2*)carve((size_t)Nt * 8);
  int*  bkt     = (int*)carve((size_t)NB * BCAP * 4);
  float* hidp1  = (float*)carve((size_t)Nn * 128 * 4);
  (void)ws_size; (void)n_in;

  const int* ei0 = (const int*)d_in[1];
  const int* ei1 = (const int*)d_in[7];
  const int* ei2 = (const int*)d_in[13];

  // bucketed adjacency build
  const int ncnt = NB * SLICES * 16;
  zeroB<<<(ncnt + 255) / 256, 256, 0, stream>>>(bktCnt, ncnt);
  scatter_p<<<(totE + STB - 1) / STB, SBS, 0, stream>>>(
      ei0, ei1, ei2, E0, E1, E2, nbpc, bktCnt, bkt);
  sortbkt<<<NB, 256, 0, stream>>>(bkt, bktCnt, offcnt3, Nn, nbpc);

  for (int cat = 0; cat < 3; ++cat) {
    const float* x   = (const float*)d_in[6 * cat + 0];
    const float* W   = (const float*)d_in[6 * cat + 2];
    const float* ats = (const float*)d_in[6 * cat + 3];
    const float* atd = (const float*)d_in[6 * cat + 4];
    const int K = in_sizes[6 * cat] / Nn;
    float* a_src_c = a_src3 + (size_t)cat * Nn * 2;
    float* a_dst_c = a_dst3 + (size_t)cat * Nn * 2;

    gemm_att<<<(Nn + TM - 1) / TM, 256, 0, stream>>>(
        x, W, ats, atd, xw, a_src_c, a_dst_c, Nn, K);
    aggregate<<<((size_t)Nn * 64 + 255) / 256, 256, 0, stream>>>(
        xw, a_src_c, a_dst_c, offcnt3 + (size_t)cat * Nn, bkt,
        agg3 + (size_t)cat * Nn * 128, Nn);
  }

  // split-K MLP: khalf0 partial reuses the (now dead) xw buffer
  dim3 gpart((Nn + FTM - 1) / FTM, 2);
  final_mlp_part<<<gpart, 256, 0, stream>>>(
      agg3, agg3 + (size_t)Nn * 128, agg3 + (size_t)2 * Nn * 128,
      (const float*)d_in[5], (const float*)d_in[11], (const float*)d_in[17],
      (const float*)d_in[18], xw, hidp1, Nn);
  mlp_tail<<<(Nn + 3) / 4, 256, 0, stream>>>(
      xw, hidp1, (const float*)d_in[19], (const float*)d_in[20],
      (const float*)d_in[21], (float*)d_out, Nn);
}

// Round 6
// 416.671 us; speedup vs baseline: 1.0324x; 1.0324x over previous
//
#include <hip/hip_runtime.h>
#include <cstdint>
#include <cstddef>

// ---------------------------------------------------------------------------
// FCAGAT: 3x GATConv (H=2, C=64) + ELU + concat + MLP(384->128->1)
// R8: scatter_p LDS radix-partition (was 92.7us scatter_b, 8x write amp).
// R9/R10: final_mlp split-K variants regressed; single-kernel form is best.
// R11: aggregate float2 gather FAILED (absmax 0.67): __shfl inside a
// lane-divergent ternary -> clang branches on h0 -> ds_bpermute from
// EXEC-inactive source lanes returns 0 on gfx950 -> half the weights zeroed
// for nodes with >32 edges. R12 fix: broadcast BOTH head weights
// unconditionally (convergent, full exec), then v_cndmask select.
// VMEM win kept: 4x dwordx2 loads + float2 store per 4 edges (was 8x dword
// + 2 stores). NEVER put __shfl in divergent control flow.
//   K1 zeroB      : bktCnt = 0   (one counter per 64B line)
//   K2 scatter_p  : LDS-partitioned edge scatter -> (bucket,slice) runs
//   K3 sortbkt    : read 8 slices, LDS counting sort by dLow + self-loop inj
//   K4 gemm_att   : xw = x@W tiled GEMM (swizzled LDS) + fused att dots
//   K5 aggregate  : wave/node: lane-parallel online softmax + float2 gather
//   K6 final_mlp  : tiled GEMM elu(agg+b)[N,384]@Wc1 + fused relu/Wc2 epilogue
// ---------------------------------------------------------------------------

__device__ __forceinline__ float lrelu02(float x) { return x > 0.f ? x : 0.2f * x; }
__device__ __forceinline__ float elu1(float x) { return x > 0.f ? x : (__expf(x) - 1.f); }

#define TM 64
#define TN 128
#define TKK 32
#define SLICES 8
#define CAPX 448               // per-(bucket,slice): mean ~240, +13 sigma
#define BCAP (SLICES * CAPX)   // 3584 >= max bucket total (~2046)

#define SBS 512                // scatter block threads
#define SEPT 16                // edges per thread
#define STB (SBS * SEPT)       // 8192 edges per block
#define NBINS_PAD 1024         // >= 3*nbpc = 939, padded pow2

// ---------------- K4: XW = X[M,K] @ W[K,128] + fused attention dots ----------
__global__ __launch_bounds__(256) void gemm_att(
    const float* __restrict__ X, const float* __restrict__ W,
    const float* __restrict__ att_s, const float* __restrict__ att_d,
    float* __restrict__ XW, float* __restrict__ a_src, float* __restrict__ a_dst,
    int M, int K) {
  __shared__ __align__(16) float xs[TKK][TM];     // 8 KB, swizzled transposed A
  __shared__ __align__(16) float4 wsB[TKK][TN/4]; // 16 KB, swizzled B
  const int tid = threadIdx.x;
  const int tx = tid & 15;
  const int ty = tid >> 4;
  const int row0 = blockIdx.x * TM;
  float acc[4][8];
#pragma unroll
  for (int r = 0; r < 4; ++r)
#pragma unroll
    for (int c = 0; c < 8; ++c) acc[r][c] = 0.f;

  const int lr = tid >> 2;
  const int lk = (tid & 3) * 8;
  const int wr = tid >> 3;
  const int bb = (tid & 7) * 4;
  const int xcol = lr ^ (((lk >> 3) & 1) * 16);
  const int p0 = (tx * 2) ^ (2 * ((tx * 2) >> 3));
  const int p1 = (tx * 2 + 1) ^ (2 * ((tx * 2 + 1) >> 3));

  for (int k0 = 0; k0 < K; k0 += TKK) {
    int xrow = row0 + lr; if (xrow >= M) xrow = M - 1;
    const float4* xp = (const float4*)(X + (size_t)xrow * K + k0 + lk);
    float4 xa = xp[0];
    float4 xb = xp[1];
    const float4* wp = (const float4*)(W + (size_t)(k0 + wr) * TN + bb * 4);
    float4 w0 = wp[0], w1 = wp[1], w2 = wp[2], w3 = wp[3];
    __syncthreads();
    xs[lk + 0][xcol] = xa.x; xs[lk + 1][xcol] = xa.y;
    xs[lk + 2][xcol] = xa.z; xs[lk + 3][xcol] = xa.w;
    xs[lk + 4][xcol] = xb.x; xs[lk + 5][xcol] = xb.y;
    xs[lk + 6][xcol] = xb.z; xs[lk + 7][xcol] = xb.w;
    {
      int b0i = bb + 0; wsB[wr][b0i ^ (2 * (b0i >> 3))] = w0;
      int b1i = bb + 1; wsB[wr][b1i ^ (2 * (b1i >> 3))] = w1;
      int b2i = bb + 2; wsB[wr][b2i ^ (2 * (b2i >> 3))] = w2;
      int b3i = bb + 3; wsB[wr][b3i ^ (2 * (b3i >> 3))] = w3;
    }
    __syncthreads();
#pragma unroll
    for (int k = 0; k < TKK; ++k) {
      const int acol = (ty * 4) ^ (((k >> 3) & 1) * 16);
      float4 a = *(const float4*)&xs[k][acol];
      float4 b0 = wsB[k][p0];
      float4 b1 = wsB[k][p1];
      float av[4] = {a.x, a.y, a.z, a.w};
      float bv[8] = {b0.x, b0.y, b0.z, b0.w, b1.x, b1.y, b1.z, b1.w};
#pragma unroll
      for (int r = 0; r < 4; ++r)
#pragma unroll
        for (int c = 0; c < 8; ++c)
          acc[r][c] = fmaf(av[r], bv[c], acc[r][c]);
    }
  }
#pragma unroll
  for (int r = 0; r < 4; ++r) {
    int row = row0 + ty * 4 + r;
    if (row < M) {
      float4 o0 = {acc[r][0], acc[r][1], acc[r][2], acc[r][3]};
      float4 o1 = {acc[r][4], acc[r][5], acc[r][6], acc[r][7]};
      float4* op = (float4*)(XW + (size_t)row * TN + tx * 8);
      op[0] = o0; op[1] = o1;
    }
  }
  // fused attention dots: this thread's 8 cols all belong to head tx>>3
  float ps[4] = {0.f, 0.f, 0.f, 0.f}, pd[4] = {0.f, 0.f, 0.f, 0.f};
#pragma unroll
  for (int c = 0; c < 8; ++c) {
    float as = att_s[tx * 8 + c], ad = att_d[tx * 8 + c];
#pragma unroll
    for (int r = 0; r < 4; ++r) {
      ps[r] = fmaf(acc[r][c], as, ps[r]);
      pd[r] = fmaf(acc[r][c], ad, pd[r]);
    }
  }
#pragma unroll
  for (int off = 1; off < 8; off <<= 1) {
#pragma unroll
    for (int r = 0; r < 4; ++r) {
      ps[r] += __shfl_xor(ps[r], off);
      pd[r] += __shfl_xor(pd[r], off);
    }
  }
  if ((tx & 7) == 0) {
    int head = tx >> 3;
#pragma unroll
    for (int r = 0; r < 4; ++r) {
      int row = row0 + ty * 4 + r;
      if (row < M) {
        a_src[row * 2 + head] = ps[r];
        a_dst[row * 2 + head] = pd[r];
      }
    }
  }
}

// ---------------- K1: zero (line-padded) bucket counters ----------------
__global__ void zeroB(int* __restrict__ a, int n) {
  int i = blockIdx.x * blockDim.x + threadIdx.x;
  if (i < n) a[i] = 0;
}

// ---------------- K2: LDS radix-partition edge scatter ----------------
__global__ __launch_bounds__(512) void scatter_p(
    const int* __restrict__ ei0, const int* __restrict__ ei1,
    const int* __restrict__ ei2, int E0, int E1, int E2,
    int nbpc, int* __restrict__ bktCnt, int* __restrict__ bkt) {
  __shared__ int hist[NBINS_PAD];
  __shared__ int binStart[NBINS_PAD];
  __shared__ int binResv[NBINS_PAD];
  __shared__ int fillB[NBINS_PAD];
  __shared__ int scanBuf[SBS];
  __shared__ int stage[STB];
  __shared__ int gdst[STB];
  const int tid = threadIdx.x;
  const int slice = blockIdx.x & (SLICES - 1);   // ~= XCD id (round-robin)
  const int nbins = 3 * nbpc;
  const int c1 = E0, c2 = E0 + E1, totE = c2 + E2;
  const int eb = blockIdx.x * STB;

  for (int b = tid; b < NBINS_PAD; b += SBS) hist[b] = 0;
  __syncthreads();

  // load 16 edges/thread, histogram bins
  int binv[SEPT], payv[SEPT];
#pragma unroll
  for (int k = 0; k < SEPT; ++k) {
    int g = eb + k * SBS + tid;
    int bn = -1, pay = 0;
    if (g < totE) {
      int s, d, cat;
      if (g < c1)      { s = ei0[g]; d = ei0[E0 + g]; cat = 0; }
      else if (g < c2) { int t = g - c1; s = ei1[t]; d = ei1[E1 + t]; cat = 1; }
      else             { int t = g - c2; s = ei2[t]; d = ei2[E2 + t]; cat = 2; }
      bn = cat * nbpc + (d >> 7);
      pay = ((d & 127) << 16) | s;
      atomicAdd(&hist[bn], 1);
    }
    binv[k] = bn; payv[k] = pay;
  }
  __syncthreads();

  // exclusive scan of hist -> binStart (2 bins/thread, Hillis-Steele on 512)
  const int a0 = hist[tid * 2], a1 = hist[tid * 2 + 1];
  scanBuf[tid] = a0 + a1;
  __syncthreads();
  for (int off = 1; off < SBS; off <<= 1) {
    int v = (tid >= off) ? scanBuf[tid - off] : 0;
    __syncthreads();
    scanBuf[tid] += v;
    __syncthreads();
  }
  const int total = scanBuf[SBS - 1];
  const int base = (tid > 0) ? scanBuf[tid - 1] : 0;
  binStart[tid * 2] = base;
  binStart[tid * 2 + 1] = base + a0;

  // reserve a contiguous run per non-empty bin (XCD-private slice counters)
  for (int b = tid; b < NBINS_PAD; b += SBS) {
    fillB[b] = 0;
    int c = hist[b];
    if (c > 0 && b < nbins)
      binResv[b] = atomicAdd(&bktCnt[(b * SLICES + slice) * 16], c);
  }
  __syncthreads();

  // counting-sort edges into LDS stage, record global destination
#pragma unroll
  for (int k = 0; k < SEPT; ++k) {
    int bn = binv[k];
    if (bn >= 0) {
      int f = atomicAdd(&fillB[bn], 1);
      int p = binStart[bn] + f;
      int go = binResv[bn] + f;
      stage[p] = payv[k];
      gdst[p] = (go < CAPX) ? ((bn * SLICES + slice) * CAPX + go) : -1;
    }
  }
  __syncthreads();

  // run-ordered write-out: consecutive lanes -> consecutive addresses
  for (int i = tid; i < total; i += SBS) {
    int g = gdst[i];
    if (g >= 0) bkt[g] = stage[i];
  }
}

// ---------------- K3: merge slices, LDS counting sort, compact in place -----
// Self-loops injected analytically: cntA init = 1, self-loop src at slot
// scanA[t]-1 (edges fill relative slots 0..cntA-2 via fillA).
__global__ __launch_bounds__(256) void sortbkt(
    int* __restrict__ bkt, const int* __restrict__ bktCnt,
    int2* __restrict__ offcnt, int Nn, int nbpc) {
  __shared__ int cntA[128], scanA[128], fillA[128];
  __shared__ int esort[BCAP];
  const int tid = threadIdx.x;
  const int b = blockIdx.x;
  const int cat = b / nbpc, bl = b - cat * nbpc, dBase = bl << 7;
  if (tid < 128) {
    cntA[tid] = (dBase + tid < Nn) ? 1 : 0;   // self-loop
    fillA[tid] = 0;
  }
  __syncthreads();
  int ns[SLICES];
#pragma unroll
  for (int s = 0; s < SLICES; ++s)
    ns[s] = min(bktCnt[(b * SLICES + s) * 16], CAPX);
  // pass 1: histogram by dLow
#pragma unroll
  for (int s = 0; s < SLICES; ++s) {
    const int* seg = bkt + (size_t)(b * SLICES + s) * CAPX;
    for (int i = tid; i < ns[s]; i += 256) atomicAdd(&cntA[seg[i] >> 16], 1);
  }
  __syncthreads();
  if (tid < 128) scanA[tid] = cntA[tid];
  __syncthreads();
  for (int off = 1; off < 128; off <<= 1) {
    int t = (tid < 128 && tid >= off) ? scanA[tid - off] : 0;
    __syncthreads();
    if (tid < 128) scanA[tid] += t;
    __syncthreads();
  }
  // pass 2: place edges (exclusive start for node t = scanA[t]-cntA[t])
#pragma unroll
  for (int s = 0; s < SLICES; ++s) {
    const int* seg = bkt + (size_t)(b * SLICES + s) * CAPX;
    for (int i = tid; i < ns[s]; i += 256) {
      int v = seg[i];
      int n = v >> 16;
      int p = scanA[n] - cntA[n] + atomicAdd(&fillA[n], 1);
      esort[p] = v & 0xFFFF;
    }
  }
  // self-loop: last slot of node's segment
  if (tid < 128 && dBase + tid < Nn) esort[scanA[tid] - 1] = dBase + tid;
  __syncthreads();
  const int tot = scanA[127];
  int* outp = bkt + (size_t)b * BCAP;     // compact to bucket base
  for (int i = tid; i < tot; i += 256) outp[i] = esort[i];
  if (tid < 128 && dBase + tid < Nn)
    offcnt[(size_t)cat * Nn + dBase + tid] =
        make_int2(b * BCAP + scanA[tid] - cntA[tid], cntA[tid]);
}

// ---------------- K5: lane-parallel segment softmax + float2 gather ---------
// Phase 2: lane l accumulates cols (2l, 2l+1) -> ONE dwordx2 per edge per
// lane. Head weight: lane<32 -> head0, else head1. Both head weights are
// broadcast UNCONDITIONALLY (convergent shfl at full exec), THEN selected --
// gfx950 ds_bpermute from an EXEC-inactive source lane returns 0, so __shfl
// must never sit inside lane-divergent control flow (R11 bug).
__global__ __launch_bounds__(256) void aggregate(
    const float* __restrict__ xw, const float* __restrict__ a_src,
    const float* __restrict__ a_dst, const int2* __restrict__ offcnt,
    const int* __restrict__ adjS, float* __restrict__ agg, int Nn) {
  const int node = (int)((blockIdx.x * (size_t)blockDim.x + threadIdx.x) >> 6);
  const int lane = threadIdx.x & 63;
  if (node >= Nn) return;
  const int2 oc = offcnt[node];
  const int base = oc.x, end = oc.x + oc.y;
  const float2 ad = ((const float2*)a_dst)[node];

  // phase 1: lane-strided online softmax stats; keep first chunk in regs
  float m0 = -1e30f, s0 = 0.f, m1 = -1e30f, s1 = 0.f;
  int sv0 = 0; float ex0 = -1e30f, ey0 = -1e30f;
  for (int cb = base; cb < end; cb += 64) {
    int j = cb + lane;
    int sv = 0; float ex = -1e30f, ey = -1e30f;
    if (j < end) {
      sv = adjS[j];
      float2 as = ((const float2*)a_src)[sv];
      ex = lrelu02(as.x + ad.x);
      ey = lrelu02(as.y + ad.y);
      float nm0 = fmaxf(m0, ex);
      s0 = s0 * __expf(m0 - nm0) + __expf(ex - nm0); m0 = nm0;
      float nm1 = fmaxf(m1, ey);
      s1 = s1 * __expf(m1 - nm1) + __expf(ey - nm1); m1 = nm1;
    }
    if (cb == base) { sv0 = sv; ex0 = ex; ey0 = ey; }
  }
#pragma unroll
  for (int off = 32; off; off >>= 1) {
    float om0 = __shfl_xor(m0, off), os0 = __shfl_xor(s0, off);
    float nm0 = fmaxf(m0, om0);
    s0 = s0 * __expf(m0 - nm0) + os0 * __expf(om0 - nm0); m0 = nm0;
    float om1 = __shfl_xor(m1, off), os1 = __shfl_xor(s1, off);
    float nm1 = fmaxf(m1, om1);
    s1 = s1 * __expf(m1 - nm1) + os1 * __expf(om1 - nm1); m1 = nm1;
  }
  const float inv0 = 1.f / s0, inv1 = 1.f / s1;
  const bool h0 = (lane < 32);   // this lane's cols (2l,2l+1): head0 if l<32

  // phase 2: weight once per edge (its lane), shfl-broadcast, float2 gather x4
  float2 acc = {0.f, 0.f};
  for (int cb = base; cb < end; cb += 64) {
    const int cnt = min(64, end - cb);
    int srcv; float w0v, w1v;
    if (cb == base) {
      srcv = sv0;
      w0v = __expf(ex0 - m0) * inv0;   // inactive lanes: exp(-inf)=0
      w1v = __expf(ey0 - m1) * inv1;
    } else {
      srcv = 0; float ex = -1e30f, ey = -1e30f;
      if (lane < cnt) {
        srcv = adjS[cb + lane];
        float2 as = ((const float2*)a_src)[srcv];
        ex = lrelu02(as.x + ad.x);
        ey = lrelu02(as.y + ad.y);
      }
      w0v = __expf(ex - m0) * inv0;
      w1v = __expf(ey - m1) * inv1;
    }
    int k = 0;
    for (; k + 4 <= cnt; k += 4) {
      int sa = __shfl(srcv, k),     sb = __shfl(srcv, k + 1);
      int sc = __shfl(srcv, k + 2), sd = __shfl(srcv, k + 3);
      float2 va = ((const float2*)(xw + (size_t)sa * 128))[lane];
      float2 vb = ((const float2*)(xw + (size_t)sb * 128))[lane];
      float2 vc = ((const float2*)(xw + (size_t)sc * 128))[lane];
      float2 vd = ((const float2*)(xw + (size_t)sd * 128))[lane];
      // convergent: both heads' weights broadcast at full exec, then select
      float w0a = __shfl(w0v, k),     w1a = __shfl(w1v, k);
      float w0b = __shfl(w0v, k + 1), w1b = __shfl(w1v, k + 1);
      float w0c = __shfl(w0v, k + 2), w1c = __shfl(w1v, k + 2);
      float w0d = __shfl(w0v, k + 3), w1d = __shfl(w1v, k + 3);
      float wa = h0 ? w0a : w1a;
      float wb = h0 ? w0b : w1b;
      float wc = h0 ? w0c : w1c;
      float wd = h0 ? w0d : w1d;
      acc.x = fmaf(wa, va.x, acc.x); acc.y = fmaf(wa, va.y, acc.y);
      acc.x = fmaf(wb, vb.x, acc.x); acc.y = fmaf(wb, vb.y, acc.y);
      acc.x = fmaf(wc, vc.x, acc.x); acc.y = fmaf(wc, vc.y, acc.y);
      acc.x = fmaf(wd, vd.x, acc.x); acc.y = fmaf(wd, vd.y, acc.y);
    }
    for (; k < cnt; ++k) {
      int s = __shfl(srcv, k);
      float w0b_ = __shfl(w0v, k), w1b_ = __shfl(w1v, k);
      float w = h0 ? w0b_ : w1b_;
      float2 v = ((const float2*)(xw + (size_t)s * 128))[lane];
      acc.x = fmaf(w, v.x, acc.x);
      acc.y = fmaf(w, v.y, acc.y);
    }
  }
  ((float2*)(agg + (size_t)node * 128))[lane] = acc;
}

// ---------------- K6: final MLP as tiled GEMM, swizzled LDS ----------------
__global__ __launch_bounds__(256) void final_mlp(
    const float* __restrict__ agg0, const float* __restrict__ agg1,
    const float* __restrict__ agg2, const float* __restrict__ bias0,
    const float* __restrict__ bias1, const float* __restrict__ bias2,
    const float* __restrict__ Wc1, const float* __restrict__ bc1,
    const float* __restrict__ Wc2, const float* __restrict__ bc2,
    float* __restrict__ out, int Nn) {
  __shared__ __align__(16) float xs[TKK][TM];
  __shared__ __align__(16) float4 wsB[TKK][TN/4];
  __shared__ float red[TM][17];
  const int tid = threadIdx.x;
  const int tx = tid & 15;
  const int ty = tid >> 4;
  const int row0 = blockIdx.x * TM;
  float acc[4][8];
#pragma unroll
  for (int r = 0; r < 4; ++r)
#pragma unroll
    for (int c = 0; c < 8; ++c) acc[r][c] = 0.f;

  const int lr = tid >> 2;
  const int lk = (tid & 3) * 8;
  const int wr = tid >> 3;
  const int bb = (tid & 7) * 4;
  const int xcol = lr ^ (((lk >> 3) & 1) * 16);
  const int p0 = (tx * 2) ^ (2 * ((tx * 2) >> 3));
  const int p1 = (tx * 2 + 1) ^ (2 * ((tx * 2 + 1) >> 3));

  for (int k0 = 0; k0 < 384; k0 += TKK) {
    int row = row0 + lr; if (row >= Nn) row = Nn - 1;
    const int kg = k0 + lk;
    const int sel = kg >> 7, q = kg & 127;
    const float* aggp = (sel == 0) ? agg0 : (sel == 1) ? agg1 : agg2;
    const float* bp   = (sel == 0) ? bias0 : (sel == 1) ? bias1 : bias2;
    float4 xa = *(const float4*)(aggp + (size_t)row * 128 + q);
    float4 xb = *(const float4*)(aggp + (size_t)row * 128 + q + 4);
    float4 ba = *(const float4*)(bp + q);
    float4 bbv = *(const float4*)(bp + q + 4);
    xa.x = elu1(xa.x + ba.x); xa.y = elu1(xa.y + ba.y);
    xa.z = elu1(xa.z + ba.z); xa.w = elu1(xa.w + ba.w);
    xb.x = elu1(xb.x + bbv.x); xb.y = elu1(xb.y + bbv.y);
    xb.z = elu1(xb.z + bbv.z); xb.w = elu1(xb.w + bbv.w);
    const float4* wp = (const float4*)(Wc1 + (size_t)(k0 + wr) * TN + bb * 4);
    float4 w0 = wp[0], w1 = wp[1], w2 = wp[2], w3 = wp[3];
    __syncthreads();
    xs[lk + 0][xcol] = xa.x; xs[lk + 1][xcol] = xa.y;
    xs[lk + 2][xcol] = xa.z; xs[lk + 3][xcol] = xa.w;
    xs[lk + 4][xcol] = xb.x; xs[lk + 5][xcol] = xb.y;
    xs[lk + 6][xcol] = xb.z; xs[lk + 7][xcol] = xb.w;
    {
      int b0i = bb + 0; wsB[wr][b0i ^ (2 * (b0i >> 3))] = w0;
      int b1i = bb + 1; wsB[wr][b1i ^ (2 * (b1i >> 3))] = w1;
      int b2i = bb + 2; wsB[wr][b2i ^ (2 * (b2i >> 3))] = w2;
      int b3i = bb + 3; wsB[wr][b3i ^ (2 * (b3i >> 3))] = w3;
    }
    __syncthreads();
#pragma unroll
    for (int k = 0; k < TKK; ++k) {
      const int acol = (ty * 4) ^ (((k >> 3) & 1) * 16);
      float4 a = *(const float4*)&xs[k][acol];
      float4 b0 = wsB[k][p0];
      float4 b1 = wsB[k][p1];
      float av[4] = {a.x, a.y, a.z, a.w};
      float bv[8] = {b0.x, b0.y, b0.z, b0.w, b1.x, b1.y, b1.z, b1.w};
#pragma unroll
      for (int r = 0; r < 4; ++r)
#pragma unroll
        for (int c = 0; c < 8; ++c)
          acc[r][c] = fmaf(av[r], bv[c], acc[r][c]);
    }
  }

  float bcv[8], w2v[8];
#pragma unroll
  for (int c = 0; c < 8; ++c) {
    bcv[c] = bc1[tx * 8 + c];
    w2v[c] = Wc2[tx * 8 + c];
  }
#pragma unroll
  for (int r = 0; r < 4; ++r) {
    float p = 0.f;
#pragma unroll
    for (int c = 0; c < 8; ++c)
      p = fmaf(fmaxf(acc[r][c] + bcv[c], 0.f), w2v[c], p);
    red[ty * 4 + r][tx] = p;
  }
  __syncthreads();
  if (tid < TM) {
    float s = 0.f;
#pragma unroll
    for (int i = 0; i < 16; ++i) s += red[tid][i];
    int n = row0 + tid;
    if (n < Nn) out[n] = s + bc2[0];
  }
}

// ---------------------------------------------------------------------------
extern "C" void kernel_launch(void* const* d_in, const int* in_sizes, int n_in,
                              void* d_out, int out_size, void* d_ws, size_t ws_size,
                              hipStream_t stream) {
  const int Nn = out_size;            // 40000
  const int E0 = in_sizes[1] / 2;
  const int E1 = in_sizes[7] / 2;
  const int E2 = in_sizes[13] / 2;
  const int totE = E0 + E1 + E2;
  const int Nt = 3 * Nn;
  const int nbpc = (Nn + 127) / 128;  // buckets per category (313)
  const int NB = 3 * nbpc;            // 939

  char* base = (char*)d_ws;
  size_t off = 0;
  auto carve = [&](size_t bytes) -> void* {
    off = (off + 255) & ~(size_t)255;
    void* p = base + off;
    off += bytes;
    return p;
  };
  float* xw     = (float*)carve((size_t)Nn * 128 * 4);      // reused per cat
  float* agg3   = (float*)carve((size_t)Nt * 128 * 4);
  float* a_src3 = (float*)carve((size_t)Nt * 2 * 4);
  float* a_dst3 = (float*)carve((size_t)Nt * 2 * 4);
  int*  bktCnt  = (int*)carve((size_t)NB * SLICES * 16 * 4); // line-padded
  int2* offcnt3 = (int2*)carve((size_t)Nt * 8);
  int*  bkt     = (int*)carve((size_t)NB * BCAP * 4);
  (void)ws_size; (void)n_in;

  const int* ei0 = (const int*)d_in[1];
  const int* ei1 = (const int*)d_in[7];
  const int* ei2 = (const int*)d_in[13];

  // bucketed adjacency build
  const int ncnt = NB * SLICES * 16;
  zeroB<<<(ncnt + 255) / 256, 256, 0, stream>>>(bktCnt, ncnt);
  scatter_p<<<(totE + STB - 1) / STB, SBS, 0, stream>>>(
      ei0, ei1, ei2, E0, E1, E2, nbpc, bktCnt, bkt);
  sortbkt<<<NB, 256, 0, stream>>>(bkt, bktCnt, offcnt3, Nn, nbpc);

  for (int cat = 0; cat < 3; ++cat) {
    const float* x   = (const float*)d_in[6 * cat + 0];
    const float* W   = (const float*)d_in[6 * cat + 2];
    const float* ats = (const float*)d_in[6 * cat + 3];
    const float* atd = (const float*)d_in[6 * cat + 4];
    const int K = in_sizes[6 * cat] / Nn;
    float* a_src_c = a_src3 + (size_t)cat * Nn * 2;
    float* a_dst_c = a_dst3 + (size_t)cat * Nn * 2;

    gemm_att<<<(Nn + TM - 1) / TM, 256, 0, stream>>>(
        x, W, ats, atd, xw, a_src_c, a_dst_c, Nn, K);
    aggregate<<<((size_t)Nn * 64 + 255) / 256, 256, 0, stream>>>(
        xw, a_src_c, a_dst_c, offcnt3 + (size_t)cat * Nn, bkt,
        agg3 + (size_t)cat * Nn * 128, Nn);
  }

  final_mlp<<<(Nn + TM - 1) / TM, 256, 0, stream>>>(
      agg3, agg3 + (size_t)Nn * 128, agg3 + (size_t)2 * Nn * 128,
      (const float*)d_in[5], (const float*)d_in[11], (const float*)d_in[17],
      (const float*)d_in[18], (const float*)d_in[19],
      (const float*)d_in[20], (const float*)d_in[21],
      (float*)d_out, Nn);
}

// Round 7
// 398.332 us; speedup vs baseline: 1.0799x; 1.0460x over previous
//
#include <hip/hip_runtime.h>
#include <cstdint>
#include <cstddef>

// ---------------------------------------------------------------------------
// FCAGAT: 3x GATConv (H=2, C=64) + ELU + concat + MLP(384->128->1)
// R8: scatter_p LDS radix-partition (was 92.7us scatter_b, 8x write amp).
// R9/R10: final_mlp split-K variants regressed; single-kernel form is best
// (and has +-10% run noise: 70.4 vs 79.2 identical code/counters).
// R11/R12: aggregate float2 gather; __shfl must be hoisted out of divergent
// control flow (inactive-source bpermute returns 0 on gfx950).
// R13: xw stored as BF16 (RNE) -> aggregate's gather traffic halves
// (~336MB -> 168MB per cat from L2/L3, the dominant intrinsic cost).
// acc stays fp32 in gemm_att so a_src/a_dst are unaffected; agg + final_mlp
// remain fp32 (full-bf16 chain error ~1e-2 too close to 1.64e-2 threshold).
//   K1 zeroB      : bktCnt = 0   (one counter per 64B line)
//   K2 scatter_p  : LDS-partitioned edge scatter -> (bucket,slice) runs
//   K3 sortbkt    : read 8 slices, LDS counting sort by dLow + self-loop inj
//   K4 gemm_att   : xw(bf16) = x@W tiled GEMM + fused att dots (fp32)
//   K5 aggregate  : wave/node: lane-parallel online softmax + bf16x2 gather
//   K6 final_mlp  : tiled GEMM elu(agg+b)[N,384]@Wc1 + fused relu/Wc2 epilogue
// ---------------------------------------------------------------------------

__device__ __forceinline__ float lrelu02(float x) { return x > 0.f ? x : 0.2f * x; }
__device__ __forceinline__ float elu1(float x) { return x > 0.f ? x : (__expf(x) - 1.f); }

// bf16 pack/unpack (RNE; no NaN in this data)
__device__ __forceinline__ unsigned bfrne(float x) {
  unsigned u = __float_as_uint(x);
  return (u + 0x7FFFu + ((u >> 16) & 1u)) >> 16;
}
__device__ __forceinline__ unsigned pack2bf(float lo, float hi) {
  return bfrne(lo) | (bfrne(hi) << 16);
}
__device__ __forceinline__ float bflo2f(unsigned u) { return __uint_as_float(u << 16); }
__device__ __forceinline__ float bfhi2f(unsigned u) { return __uint_as_float(u & 0xFFFF0000u); }

#define TM 64
#define TN 128
#define TKK 32
#define SLICES 8
#define CAPX 448               // per-(bucket,slice): mean ~240, +13 sigma
#define BCAP (SLICES * CAPX)   // 3584 >= max bucket total (~2046)

#define SBS 512                // scatter block threads
#define SEPT 16                // edges per thread
#define STB (SBS * SEPT)       // 8192 edges per block
#define NBINS_PAD 1024         // >= 3*nbpc = 939, padded pow2

// ---------------- K4: XW(bf16) = X[M,K] @ W[K,128] + fused attention dots ---
__global__ __launch_bounds__(256) void gemm_att(
    const float* __restrict__ X, const float* __restrict__ W,
    const float* __restrict__ att_s, const float* __restrict__ att_d,
    unsigned short* __restrict__ XWH, float* __restrict__ a_src,
    float* __restrict__ a_dst, int M, int K) {
  __shared__ __align__(16) float xs[TKK][TM];     // 8 KB, swizzled transposed A
  __shared__ __align__(16) float4 wsB[TKK][TN/4]; // 16 KB, swizzled B
  const int tid = threadIdx.x;
  const int tx = tid & 15;
  const int ty = tid >> 4;
  const int row0 = blockIdx.x * TM;
  float acc[4][8];
#pragma unroll
  for (int r = 0; r < 4; ++r)
#pragma unroll
    for (int c = 0; c < 8; ++c) acc[r][c] = 0.f;

  const int lr = tid >> 2;
  const int lk = (tid & 3) * 8;
  const int wr = tid >> 3;
  const int bb = (tid & 7) * 4;
  const int xcol = lr ^ (((lk >> 3) & 1) * 16);
  const int p0 = (tx * 2) ^ (2 * ((tx * 2) >> 3));
  const int p1 = (tx * 2 + 1) ^ (2 * ((tx * 2 + 1) >> 3));

  for (int k0 = 0; k0 < K; k0 += TKK) {
    int xrow = row0 + lr; if (xrow >= M) xrow = M - 1;
    const float4* xp = (const float4*)(X + (size_t)xrow * K + k0 + lk);
    float4 xa = xp[0];
    float4 xb = xp[1];
    const float4* wp = (const float4*)(W + (size_t)(k0 + wr) * TN + bb * 4);
    float4 w0 = wp[0], w1 = wp[1], w2 = wp[2], w3 = wp[3];
    __syncthreads();
    xs[lk + 0][xcol] = xa.x; xs[lk + 1][xcol] = xa.y;
    xs[lk + 2][xcol] = xa.z; xs[lk + 3][xcol] = xa.w;
    xs[lk + 4][xcol] = xb.x; xs[lk + 5][xcol] = xb.y;
    xs[lk + 6][xcol] = xb.z; xs[lk + 7][xcol] = xb.w;
    {
      int b0i = bb + 0; wsB[wr][b0i ^ (2 * (b0i >> 3))] = w0;
      int b1i = bb + 1; wsB[wr][b1i ^ (2 * (b1i >> 3))] = w1;
      int b2i = bb + 2; wsB[wr][b2i ^ (2 * (b2i >> 3))] = w2;
      int b3i = bb + 3; wsB[wr][b3i ^ (2 * (b3i >> 3))] = w3;
    }
    __syncthreads();
#pragma unroll
    for (int k = 0; k < TKK; ++k) {
      const int acol = (ty * 4) ^ (((k >> 3) & 1) * 16);
      float4 a = *(const float4*)&xs[k][acol];
      float4 b0 = wsB[k][p0];
      float4 b1 = wsB[k][p1];
      float av[4] = {a.x, a.y, a.z, a.w};
      float bv[8] = {b0.x, b0.y, b0.z, b0.w, b1.x, b1.y, b1.z, b1.w};
#pragma unroll
      for (int r = 0; r < 4; ++r)
#pragma unroll
        for (int c = 0; c < 8; ++c)
          acc[r][c] = fmaf(av[r], bv[c], acc[r][c]);
    }
  }
  // bf16 store: 8 cols -> one uint4 (16B) per row per thread, coalesced
#pragma unroll
  for (int r = 0; r < 4; ++r) {
    int row = row0 + ty * 4 + r;
    if (row < M) {
      uint4 o;
      o.x = pack2bf(acc[r][0], acc[r][1]);
      o.y = pack2bf(acc[r][2], acc[r][3]);
      o.z = pack2bf(acc[r][4], acc[r][5]);
      o.w = pack2bf(acc[r][6], acc[r][7]);
      *(uint4*)(XWH + (size_t)row * 128 + tx * 8) = o;
    }
  }
  // fused attention dots (fp32 acc): this thread's 8 cols belong to head tx>>3
  float ps[4] = {0.f, 0.f, 0.f, 0.f}, pd[4] = {0.f, 0.f, 0.f, 0.f};
#pragma unroll
  for (int c = 0; c < 8; ++c) {
    float as = att_s[tx * 8 + c], ad = att_d[tx * 8 + c];
#pragma unroll
    for (int r = 0; r < 4; ++r) {
      ps[r] = fmaf(acc[r][c], as, ps[r]);
      pd[r] = fmaf(acc[r][c], ad, pd[r]);
    }
  }
#pragma unroll
  for (int off = 1; off < 8; off <<= 1) {
#pragma unroll
    for (int r = 0; r < 4; ++r) {
      ps[r] += __shfl_xor(ps[r], off);
      pd[r] += __shfl_xor(pd[r], off);
    }
  }
  if ((tx & 7) == 0) {
    int head = tx >> 3;
#pragma unroll
    for (int r = 0; r < 4; ++r) {
      int row = row0 + ty * 4 + r;
      if (row < M) {
        a_src[row * 2 + head] = ps[r];
        a_dst[row * 2 + head] = pd[r];
      }
    }
  }
}

// ---------------- K1: zero (line-padded) bucket counters ----------------
__global__ void zeroB(int* __restrict__ a, int n) {
  int i = blockIdx.x * blockDim.x + threadIdx.x;
  if (i < n) a[i] = 0;
}

// ---------------- K2: LDS radix-partition edge scatter ----------------
__global__ __launch_bounds__(512) void scatter_p(
    const int* __restrict__ ei0, const int* __restrict__ ei1,
    const int* __restrict__ ei2, int E0, int E1, int E2,
    int nbpc, int* __restrict__ bktCnt, int* __restrict__ bkt) {
  __shared__ int hist[NBINS_PAD];
  __shared__ int binStart[NBINS_PAD];
  __shared__ int binResv[NBINS_PAD];
  __shared__ int fillB[NBINS_PAD];
  __shared__ int scanBuf[SBS];
  __shared__ int stage[STB];
  __shared__ int gdst[STB];
  const int tid = threadIdx.x;
  const int slice = blockIdx.x & (SLICES - 1);   // ~= XCD id (round-robin)
  const int nbins = 3 * nbpc;
  const int c1 = E0, c2 = E0 + E1, totE = c2 + E2;
  const int eb = blockIdx.x * STB;

  for (int b = tid; b < NBINS_PAD; b += SBS) hist[b] = 0;
  __syncthreads();

  // load 16 edges/thread, histogram bins
  int binv[SEPT], payv[SEPT];
#pragma unroll
  for (int k = 0; k < SEPT; ++k) {
    int g = eb + k * SBS + tid;
    int bn = -1, pay = 0;
    if (g < totE) {
      int s, d, cat;
      if (g < c1)      { s = ei0[g]; d = ei0[E0 + g]; cat = 0; }
      else if (g < c2) { int t = g - c1; s = ei1[t]; d = ei1[E1 + t]; cat = 1; }
      else             { int t = g - c2; s = ei2[t]; d = ei2[E2 + t]; cat = 2; }
      bn = cat * nbpc + (d >> 7);
      pay = ((d & 127) << 16) | s;
      atomicAdd(&hist[bn], 1);
    }
    binv[k] = bn; payv[k] = pay;
  }
  __syncthreads();

  // exclusive scan of hist -> binStart (2 bins/thread, Hillis-Steele on 512)
  const int a0 = hist[tid * 2], a1 = hist[tid * 2 + 1];
  scanBuf[tid] = a0 + a1;
  __syncthreads();
  for (int off = 1; off < SBS; off <<= 1) {
    int v = (tid >= off) ? scanBuf[tid - off] : 0;
    __syncthreads();
    scanBuf[tid] += v;
    __syncthreads();
  }
  const int total = scanBuf[SBS - 1];
  const int base = (tid > 0) ? scanBuf[tid - 1] : 0;
  binStart[tid * 2] = base;
  binStart[tid * 2 + 1] = base + a0;

  // reserve a contiguous run per non-empty bin (XCD-private slice counters)
  for (int b = tid; b < NBINS_PAD; b += SBS) {
    fillB[b] = 0;
    int c = hist[b];
    if (c > 0 && b < nbins)
      binResv[b] = atomicAdd(&bktCnt[(b * SLICES + slice) * 16], c);
  }
  __syncthreads();

  // counting-sort edges into LDS stage, record global destination
#pragma unroll
  for (int k = 0; k < SEPT; ++k) {
    int bn = binv[k];
    if (bn >= 0) {
      int f = atomicAdd(&fillB[bn], 1);
      int p = binStart[bn] + f;
      int go = binResv[bn] + f;
      stage[p] = payv[k];
      gdst[p] = (go < CAPX) ? ((bn * SLICES + slice) * CAPX + go) : -1;
    }
  }
  __syncthreads();

  // run-ordered write-out: consecutive lanes -> consecutive addresses
  for (int i = tid; i < total; i += SBS) {
    int g = gdst[i];
    if (g >= 0) bkt[g] = stage[i];
  }
}

// ---------------- K3: merge slices, LDS counting sort, compact in place -----
// Self-loops injected analytically: cntA init = 1, self-loop src at slot
// scanA[t]-1 (edges fill relative slots 0..cntA-2 via fillA).
__global__ __launch_bounds__(256) void sortbkt(
    int* __restrict__ bkt, const int* __restrict__ bktCnt,
    int2* __restrict__ offcnt, int Nn, int nbpc) {
  __shared__ int cntA[128], scanA[128], fillA[128];
  __shared__ int esort[BCAP];
  const int tid = threadIdx.x;
  const int b = blockIdx.x;
  const int cat = b / nbpc, bl = b - cat * nbpc, dBase = bl << 7;
  if (tid < 128) {
    cntA[tid] = (dBase + tid < Nn) ? 1 : 0;   // self-loop
    fillA[tid] = 0;
  }
  __syncthreads();
  int ns[SLICES];
#pragma unroll
  for (int s = 0; s < SLICES; ++s)
    ns[s] = min(bktCnt[(b * SLICES + s) * 16], CAPX);
  // pass 1: histogram by dLow
#pragma unroll
  for (int s = 0; s < SLICES; ++s) {
    const int* seg = bkt + (size_t)(b * SLICES + s) * CAPX;
    for (int i = tid; i < ns[s]; i += 256) atomicAdd(&cntA[seg[i] >> 16], 1);
  }
  __syncthreads();
  if (tid < 128) scanA[tid] = cntA[tid];
  __syncthreads();
  for (int off = 1; off < 128; off <<= 1) {
    int t = (tid < 128 && tid >= off) ? scanA[tid - off] : 0;
    __syncthreads();
    if (tid < 128) scanA[tid] += t;
    __syncthreads();
  }
  // pass 2: place edges (exclusive start for node t = scanA[t]-cntA[t])
#pragma unroll
  for (int s = 0; s < SLICES; ++s) {
    const int* seg = bkt + (size_t)(b * SLICES + s) * CAPX;
    for (int i = tid; i < ns[s]; i += 256) {
      int v = seg[i];
      int n = v >> 16;
      int p = scanA[n] - cntA[n] + atomicAdd(&fillA[n], 1);
      esort[p] = v & 0xFFFF;
    }
  }
  // self-loop: last slot of node's segment
  if (tid < 128 && dBase + tid < Nn) esort[scanA[tid] - 1] = dBase + tid;
  __syncthreads();
  const int tot = scanA[127];
  int* outp = bkt + (size_t)b * BCAP;     // compact to bucket base
  for (int i = tid; i < tot; i += 256) outp[i] = esort[i];
  if (tid < 128 && dBase + tid < Nn)
    offcnt[(size_t)cat * Nn + dBase + tid] =
        make_int2(b * BCAP + scanA[tid] - cntA[tid], cntA[tid]);
}

// ---------------- K5: lane-parallel segment softmax + bf16x2 gather ---------
// Phase 2: lane l accumulates cols (2l, 2l+1) -> ONE dword (2 bf16) per edge
// per lane (half the bytes of fp32). Head weight: lane<32 -> head0 else
// head1; both head weights broadcast UNCONDITIONALLY (convergent shfl at
// full exec) then selected -- gfx950 bpermute from EXEC-inactive source
// lanes returns 0, so __shfl must never sit in divergent control flow.
__global__ __launch_bounds__(256) void aggregate(
    const unsigned short* __restrict__ xwh, const float* __restrict__ a_src,
    const float* __restrict__ a_dst, const int2* __restrict__ offcnt,
    const int* __restrict__ adjS, float* __restrict__ agg, int Nn) {
  const int node = (int)((blockIdx.x * (size_t)blockDim.x + threadIdx.x) >> 6);
  const int lane = threadIdx.x & 63;
  if (node >= Nn) return;
  const int2 oc = offcnt[node];
  const int base = oc.x, end = oc.x + oc.y;
  const float2 ad = ((const float2*)a_dst)[node];

  // phase 1: lane-strided online softmax stats; keep first chunk in regs
  float m0 = -1e30f, s0 = 0.f, m1 = -1e30f, s1 = 0.f;
  int sv0 = 0; float ex0 = -1e30f, ey0 = -1e30f;
  for (int cb = base; cb < end; cb += 64) {
    int j = cb + lane;
    int sv = 0; float ex = -1e30f, ey = -1e30f;
    if (j < end) {
      sv = adjS[j];
      float2 as = ((const float2*)a_src)[sv];
      ex = lrelu02(as.x + ad.x);
      ey = lrelu02(as.y + ad.y);
      float nm0 = fmaxf(m0, ex);
      s0 = s0 * __expf(m0 - nm0) + __expf(ex - nm0); m0 = nm0;
      float nm1 = fmaxf(m1, ey);
      s1 = s1 * __expf(m1 - nm1) + __expf(ey - nm1); m1 = nm1;
    }
    if (cb == base) { sv0 = sv; ex0 = ex; ey0 = ey; }
  }
#pragma unroll
  for (int off = 32; off; off >>= 1) {
    float om0 = __shfl_xor(m0, off), os0 = __shfl_xor(s0, off);
    float nm0 = fmaxf(m0, om0);
    s0 = s0 * __expf(m0 - nm0) + os0 * __expf(om0 - nm0); m0 = nm0;
    float om1 = __shfl_xor(m1, off), os1 = __shfl_xor(s1, off);
    float nm1 = fmaxf(m1, om1);
    s1 = s1 * __expf(m1 - nm1) + os1 * __expf(om1 - nm1); m1 = nm1;
  }
  const float inv0 = 1.f / s0, inv1 = 1.f / s1;
  const bool h0 = (lane < 32);   // this lane's cols (2l,2l+1): head0 if l<32

  // phase 2: weight once per edge (its lane), shfl-broadcast, bf16x2 gather x4
  float2 acc = {0.f, 0.f};
  for (int cb = base; cb < end; cb += 64) {
    const int cnt = min(64, end - cb);
    int srcv; float w0v, w1v;
    if (cb == base) {
      srcv = sv0;
      w0v = __expf(ex0 - m0) * inv0;   // inactive lanes: exp(-inf)=0
      w1v = __expf(ey0 - m1) * inv1;
    } else {
      srcv = 0; float ex = -1e30f, ey = -1e30f;
      if (lane < cnt) {
        srcv = adjS[cb + lane];
        float2 as = ((const float2*)a_src)[srcv];
        ex = lrelu02(as.x + ad.x);
        ey = lrelu02(as.y + ad.y);
      }
      w0v = __expf(ex - m0) * inv0;
      w1v = __expf(ey - m1) * inv1;
    }
    int k = 0;
    for (; k + 4 <= cnt; k += 4) {
      int sa = __shfl(srcv, k),     sb = __shfl(srcv, k + 1);
      int sc = __shfl(srcv, k + 2), sd = __shfl(srcv, k + 3);
      unsigned ua = ((const unsigned*)(xwh + (size_t)sa * 128))[lane];
      unsigned ub = ((const unsigned*)(xwh + (size_t)sb * 128))[lane];
      unsigned uc = ((const unsigned*)(xwh + (size_t)sc * 128))[lane];
      unsigned ud = ((const unsigned*)(xwh + (size_t)sd * 128))[lane];
      // convergent: both heads' weights broadcast at full exec, then select
      float w0a = __shfl(w0v, k),     w1a = __shfl(w1v, k);
      float w0b = __shfl(w0v, k + 1), w1b = __shfl(w1v, k + 1);
      float w0c = __shfl(w0v, k + 2), w1c = __shfl(w1v, k + 2);
      float w0d = __shfl(w0v, k + 3), w1d = __shfl(w1v, k + 3);
      float wa = h0 ? w0a : w1a;
      float wb = h0 ? w0b : w1b;
      float wc = h0 ? w0c : w1c;
      float wd = h0 ? w0d : w1d;
      acc.x = fmaf(wa, bflo2f(ua), acc.x); acc.y = fmaf(wa, bfhi2f(ua), acc.y);
      acc.x = fmaf(wb, bflo2f(ub), acc.x); acc.y = fmaf(wb, bfhi2f(ub), acc.y);
      acc.x = fmaf(wc, bflo2f(uc), acc.x); acc.y = fmaf(wc, bfhi2f(uc), acc.y);
      acc.x = fmaf(wd, bflo2f(ud), acc.x); acc.y = fmaf(wd, bfhi2f(ud), acc.y);
    }
    for (; k < cnt; ++k) {
      int s = __shfl(srcv, k);
      float w0b_ = __shfl(w0v, k), w1b_ = __shfl(w1v, k);
      float w = h0 ? w0b_ : w1b_;
      unsigned u = ((const unsigned*)(xwh + (size_t)s * 128))[lane];
      acc.x = fmaf(w, bflo2f(u), acc.x);
      acc.y = fmaf(w, bfhi2f(u), acc.y);
    }
  }
  ((float2*)(agg + (size_t)node * 128))[lane] = acc;
}

// ---------------- K6: final MLP as tiled GEMM, swizzled LDS ----------------
__global__ __launch_bounds__(256) void final_mlp(
    const float* __restrict__ agg0, const float* __restrict__ agg1,
    const float* __restrict__ agg2, const float* __restrict__ bias0,
    const float* __restrict__ bias1, const float* __restrict__ bias2,
    const float* __restrict__ Wc1, const float* __restrict__ bc1,
    const float* __restrict__ Wc2, const float* __restrict__ bc2,
    float* __restrict__ out, int Nn) {
  __shared__ __align__(16) float xs[TKK][TM];
  __shared__ __align__(16) float4 wsB[TKK][TN/4];
  __shared__ float red[TM][17];
  const int tid = threadIdx.x;
  const int tx = tid & 15;
  const int ty = tid >> 4;
  const int row0 = blockIdx.x * TM;
  float acc[4][8];
#pragma unroll
  for (int r = 0; r < 4; ++r)
#pragma unroll
    for (int c = 0; c < 8; ++c) acc[r][c] = 0.f;

  const int lr = tid >> 2;
  const int lk = (tid & 3) * 8;
  const int wr = tid >> 3;
  const int bb = (tid & 7) * 4;
  const int xcol = lr ^ (((lk >> 3) & 1) * 16);
  const int p0 = (tx * 2) ^ (2 * ((tx * 2) >> 3));
  const int p1 = (tx * 2 + 1) ^ (2 * ((tx * 2 + 1) >> 3));

  for (int k0 = 0; k0 < 384; k0 += TKK) {
    int row = row0 + lr; if (row >= Nn) row = Nn - 1;
    const int kg = k0 + lk;
    const int sel = kg >> 7, q = kg & 127;
    const float* aggp = (sel == 0) ? agg0 : (sel == 1) ? agg1 : agg2;
    const float* bp   = (sel == 0) ? bias0 : (sel == 1) ? bias1 : bias2;
    float4 xa = *(const float4*)(aggp + (size_t)row * 128 + q);
    float4 xb = *(const float4*)(aggp + (size_t)row * 128 + q + 4);
    float4 ba = *(const float4*)(bp + q);
    float4 bbv = *(const float4*)(bp + q + 4);
    xa.x = elu1(xa.x + ba.x); xa.y = elu1(xa.y + ba.y);
    xa.z = elu1(xa.z + ba.z); xa.w = elu1(xa.w + ba.w);
    xb.x = elu1(xb.x + bbv.x); xb.y = elu1(xb.y + bbv.y);
    xb.z = elu1(xb.z + bbv.z); xb.w = elu1(xb.w + bbv.w);
    const float4* wp = (const float4*)(Wc1 + (size_t)(k0 + wr) * TN + bb * 4);
    float4 w0 = wp[0], w1 = wp[1], w2 = wp[2], w3 = wp[3];
    __syncthreads();
    xs[lk + 0][xcol] = xa.x; xs[lk + 1][xcol] = xa.y;
    xs[lk + 2][xcol] = xa.z; xs[lk + 3][xcol] = xa.w;
    xs[lk + 4][xcol] = xb.x; xs[lk + 5][xcol] = xb.y;
    xs[lk + 6][xcol] = xb.z; xs[lk + 7][xcol] = xb.w;
    {
      int b0i = bb + 0; wsB[wr][b0i ^ (2 * (b0i >> 3))] = w0;
      int b1i = bb + 1; wsB[wr][b1i ^ (2 * (b1i >> 3))] = w1;
      int b2i = bb + 2; wsB[wr][b2i ^ (2 * (b2i >> 3))] = w2;
      int b3i = bb + 3; wsB[wr][b3i ^ (2 * (b3i >> 3))] = w3;
    }
    __syncthreads();
#pragma unroll
    for (int k = 0; k < TKK; ++k) {
      const int acol = (ty * 4) ^ (((k >> 3) & 1) * 16);
      float4 a = *(const float4*)&xs[k][acol];
      float4 b0 = wsB[k][p0];
      float4 b1 = wsB[k][p1];
      float av[4] = {a.x, a.y, a.z, a.w};
      float bv[8] = {b0.x, b0.y, b0.z, b0.w, b1.x, b1.y, b1.z, b1.w};
#pragma unroll
      for (int r = 0; r < 4; ++r)
#pragma unroll
        for (int c = 0; c < 8; ++c)
          acc[r][c] = fmaf(av[r], bv[c], acc[r][c]);
    }
  }

  float bcv[8], w2v[8];
#pragma unroll
  for (int c = 0; c < 8; ++c) {
    bcv[c] = bc1[tx * 8 + c];
    w2v[c] = Wc2[tx * 8 + c];
  }
#pragma unroll
  for (int r = 0; r < 4; ++r) {
    float p = 0.f;
#pragma unroll
    for (int c = 0; c < 8; ++c)
      p = fmaf(fmaxf(acc[r][c] + bcv[c], 0.f), w2v[c], p);
    red[ty * 4 + r][tx] = p;
  }
  __syncthreads();
  if (tid < TM) {
    float s = 0.f;
#pragma unroll
    for (int i = 0; i < 16; ++i) s += red[tid][i];
    int n = row0 + tid;
    if (n < Nn) out[n] = s + bc2[0];
  }
}

// ---------------------------------------------------------------------------
extern "C" void kernel_launch(void* const* d_in, const int* in_sizes, int n_in,
                              void* d_out, int out_size, void* d_ws, size_t ws_size,
                              hipStream_t stream) {
  const int Nn = out_size;            // 40000
  const int E0 = in_sizes[1] / 2;
  const int E1 = in_sizes[7] / 2;
  const int E2 = in_sizes[13] / 2;
  const int totE = E0 + E1 + E2;
  const int Nt = 3 * Nn;
  const int nbpc = (Nn + 127) / 128;  // buckets per category (313)
  const int NB = 3 * nbpc;            // 939

  char* base = (char*)d_ws;
  size_t off = 0;
  auto carve = [&](size_t bytes) -> void* {
    off = (off + 255) & ~(size_t)255;
    void* p = base + off;
    off += bytes;
    return p;
  };
  unsigned short* xwh = (unsigned short*)carve((size_t)Nn * 128 * 2); // bf16
  float* agg3   = (float*)carve((size_t)Nt * 128 * 4);
  float* a_src3 = (float*)carve((size_t)Nt * 2 * 4);
  float* a_dst3 = (float*)carve((size_t)Nt * 2 * 4);
  int*  bktCnt  = (int*)carve((size_t)NB * SLICES * 16 * 4); // line-padded
  int2* offcnt3 = (int2*)carve((size_t)Nt * 8);
  int*  bkt     = (int*)carve((size_t)NB * BCAP * 4);
  (void)ws_size; (void)n_in;

  const int* ei0 = (const int*)d_in[1];
  const int* ei1 = (const int*)d_in[7];
  const int* ei2 = (const int*)d_in[13];

  // bucketed adjacency build
  const int ncnt = NB * SLICES * 16;
  zeroB<<<(ncnt + 255) / 256, 256, 0, stream>>>(bktCnt, ncnt);
  scatter_p<<<(totE + STB - 1) / STB, SBS, 0, stream>>>(
      ei0, ei1, ei2, E0, E1, E2, nbpc, bktCnt, bkt);
  sortbkt<<<NB, 256, 0, stream>>>(bkt, bktCnt, offcnt3, Nn, nbpc);

  for (int cat = 0; cat < 3; ++cat) {
    const float* x   = (const float*)d_in[6 * cat + 0];
    const float* W   = (const float*)d_in[6 * cat + 2];
    const float* ats = (const float*)d_in[6 * cat + 3];
    const float* atd = (const float*)d_in[6 * cat + 4];
    const int K = in_sizes[6 * cat] / Nn;
    float* a_src_c = a_src3 + (size_t)cat * Nn * 2;
    float* a_dst_c = a_dst3 + (size_t)cat * Nn * 2;

    gemm_att<<<(Nn + TM - 1) / TM, 256, 0, stream>>>(
        x, W, ats, atd, xwh, a_src_c, a_dst_c, Nn, K);
    aggregate<<<((size_t)Nn * 64 + 255) / 256, 256, 0, stream>>>(
        xwh, a_src_c, a_dst_c, offcnt3 + (size_t)cat * Nn, bkt,
        agg3 + (size_t)cat * Nn * 128, Nn);
  }

  final_mlp<<<(Nn + TM - 1) / TM, 256, 0, stream>>>(
      agg3, agg3 + (size_t)Nn * 128, agg3 + (size_t)2 * Nn * 128,
      (const float*)d_in[5], (const float*)d_in[11], (const float*)d_in[17],
      (const float*)d_in[18], (const float*)d_in[19],
      (const float*)d_in[20], (const float*)d_in[21],
      (float*)d_out, Nn);
}

// Round 8
// 348.765 us; speedup vs baseline: 1.2334x; 1.1421x over previous
//
#include <hip/hip_runtime.h>
#include <cstdint>
#include <cstddef>

// ---------------------------------------------------------------------------
// FCAGAT: 3x GATConv (H=2, C=64) + ELU + concat + MLP(384->128->1)
// R8: scatter_p LDS radix-partition. R9/R10: fp32 final_mlp restructures all
// land 65-73us -> fp32 path is a dead end. R11/R12: __shfl must stay out of
// divergent control flow (inactive-source bpermute returns 0). R13: bf16 xw
// gather (398us, absmax 3.9e-3 of 1.64e-2 -> 4x headroom).
// R14: final_mlp -> MFMA bf16. aggregate emits ah[N][384] = bf16(elu(acc+
// bias)) directly (elu fused where VALU idle; agg3 fp32 dies). Wc1 pre-
// swizzled once into bf16 B-fragment order (96KB, L2-hot). final_mlp_mfma:
// 4 waves/block, wave = 16 rows x 128 cols via 8x mfma_f32_16x16x32_bf16
// per K-step; A-frags from global (row read once), B-frags from L2-hot
// swizzled global; NO LDS, NO barriers. Layouts per m89: A row=l&15,
// k=(l>>4)*8+j; B k=(l>>4)*8+j, col=l&15; D col=l&15, row=(l>>4)*4+r.
//   K1 zeroB        : bktCnt = 0
//   K1b wc1_swz     : Wc1 fp32 -> bf16 MFMA-fragment order (once)
//   K2 scatter_p    : LDS-partitioned edge scatter -> (bucket,slice) runs
//   K3 sortbkt      : merge slices, LDS counting sort + self-loop inject
//   K4 gemm_att     : xw(bf16) = x@W tiled GEMM + fused att dots (fp32)
//   K5 aggregate    : wave/node softmax + bf16x2 gather -> ah bf16 elu'd
//   K6 final_mlp_mfma: ah[N,384](bf16) @ Wc1(bf16) MFMA + relu/Wc2 epilogue
// ---------------------------------------------------------------------------

__device__ __forceinline__ float lrelu02(float x) { return x > 0.f ? x : 0.2f * x; }
__device__ __forceinline__ float elu1(float x) { return x > 0.f ? x : (__expf(x) - 1.f); }

// bf16 pack/unpack (RNE; no NaN in this data)
__device__ __forceinline__ unsigned bfrne(float x) {
  unsigned u = __float_as_uint(x);
  return (u + 0x7FFFu + ((u >> 16) & 1u)) >> 16;
}
__device__ __forceinline__ unsigned pack2bf(float lo, float hi) {
  return bfrne(lo) | (bfrne(hi) << 16);
}
__device__ __forceinline__ float bflo2f(unsigned u) { return __uint_as_float(u << 16); }
__device__ __forceinline__ float bfhi2f(unsigned u) { return __uint_as_float(u & 0xFFFF0000u); }

typedef __attribute__((ext_vector_type(8))) short short8;
typedef __attribute__((ext_vector_type(4))) float f32x4;

#define TM 64
#define TN 128
#define TKK 32
#define SLICES 8
#define CAPX 448               // per-(bucket,slice): mean ~240, +13 sigma
#define BCAP (SLICES * CAPX)   // 3584 >= max bucket total (~2046)

#define SBS 512                // scatter block threads
#define SEPT 16                // edges per thread
#define STB (SBS * SEPT)       // 8192 edges per block
#define NBINS_PAD 1024         // >= 3*nbpc = 939, padded pow2

// ---------------- K4: XW(bf16) = X[M,K] @ W[K,128] + fused attention dots ---
__global__ __launch_bounds__(256) void gemm_att(
    const float* __restrict__ X, const float* __restrict__ W,
    const float* __restrict__ att_s, const float* __restrict__ att_d,
    unsigned short* __restrict__ XWH, float* __restrict__ a_src,
    float* __restrict__ a_dst, int M, int K) {
  __shared__ __align__(16) float xs[TKK][TM];     // 8 KB, swizzled transposed A
  __shared__ __align__(16) float4 wsB[TKK][TN/4]; // 16 KB, swizzled B
  const int tid = threadIdx.x;
  const int tx = tid & 15;
  const int ty = tid >> 4;
  const int row0 = blockIdx.x * TM;
  float acc[4][8];
#pragma unroll
  for (int r = 0; r < 4; ++r)
#pragma unroll
    for (int c = 0; c < 8; ++c) acc[r][c] = 0.f;

  const int lr = tid >> 2;
  const int lk = (tid & 3) * 8;
  const int wr = tid >> 3;
  const int bb = (tid & 7) * 4;
  const int xcol = lr ^ (((lk >> 3) & 1) * 16);
  const int p0 = (tx * 2) ^ (2 * ((tx * 2) >> 3));
  const int p1 = (tx * 2 + 1) ^ (2 * ((tx * 2 + 1) >> 3));

  for (int k0 = 0; k0 < K; k0 += TKK) {
    int xrow = row0 + lr; if (xrow >= M) xrow = M - 1;
    const float4* xp = (const float4*)(X + (size_t)xrow * K + k0 + lk);
    float4 xa = xp[0];
    float4 xb = xp[1];
    const float4* wp = (const float4*)(W + (size_t)(k0 + wr) * TN + bb * 4);
    float4 w0 = wp[0], w1 = wp[1], w2 = wp[2], w3 = wp[3];
    __syncthreads();
    xs[lk + 0][xcol] = xa.x; xs[lk + 1][xcol] = xa.y;
    xs[lk + 2][xcol] = xa.z; xs[lk + 3][xcol] = xa.w;
    xs[lk + 4][xcol] = xb.x; xs[lk + 5][xcol] = xb.y;
    xs[lk + 6][xcol] = xb.z; xs[lk + 7][xcol] = xb.w;
    {
      int b0i = bb + 0; wsB[wr][b0i ^ (2 * (b0i >> 3))] = w0;
      int b1i = bb + 1; wsB[wr][b1i ^ (2 * (b1i >> 3))] = w1;
      int b2i = bb + 2; wsB[wr][b2i ^ (2 * (b2i >> 3))] = w2;
      int b3i = bb + 3; wsB[wr][b3i ^ (2 * (b3i >> 3))] = w3;
    }
    __syncthreads();
#pragma unroll
    for (int k = 0; k < TKK; ++k) {
      const int acol = (ty * 4) ^ (((k >> 3) & 1) * 16);
      float4 a = *(const float4*)&xs[k][acol];
      float4 b0 = wsB[k][p0];
      float4 b1 = wsB[k][p1];
      float av[4] = {a.x, a.y, a.z, a.w};
      float bv[8] = {b0.x, b0.y, b0.z, b0.w, b1.x, b1.y, b1.z, b1.w};
#pragma unroll
      for (int r = 0; r < 4; ++r)
#pragma unroll
        for (int c = 0; c < 8; ++c)
          acc[r][c] = fmaf(av[r], bv[c], acc[r][c]);
    }
  }
  // bf16 store: 8 cols -> one uint4 (16B) per row per thread, coalesced
#pragma unroll
  for (int r = 0; r < 4; ++r) {
    int row = row0 + ty * 4 + r;
    if (row < M) {
      uint4 o;
      o.x = pack2bf(acc[r][0], acc[r][1]);
      o.y = pack2bf(acc[r][2], acc[r][3]);
      o.z = pack2bf(acc[r][4], acc[r][5]);
      o.w = pack2bf(acc[r][6], acc[r][7]);
      *(uint4*)(XWH + (size_t)row * 128 + tx * 8) = o;
    }
  }
  // fused attention dots (fp32 acc): this thread's 8 cols belong to head tx>>3
  float ps[4] = {0.f, 0.f, 0.f, 0.f}, pd[4] = {0.f, 0.f, 0.f, 0.f};
#pragma unroll
  for (int c = 0; c < 8; ++c) {
    float as = att_s[tx * 8 + c], ad = att_d[tx * 8 + c];
#pragma unroll
    for (int r = 0; r < 4; ++r) {
      ps[r] = fmaf(acc[r][c], as, ps[r]);
      pd[r] = fmaf(acc[r][c], ad, pd[r]);
    }
  }
#pragma unroll
  for (int off = 1; off < 8; off <<= 1) {
#pragma unroll
    for (int r = 0; r < 4; ++r) {
      ps[r] += __shfl_xor(ps[r], off);
      pd[r] += __shfl_xor(pd[r], off);
    }
  }
  if ((tx & 7) == 0) {
    int head = tx >> 3;
#pragma unroll
    for (int r = 0; r < 4; ++r) {
      int row = row0 + ty * 4 + r;
      if (row < M) {
        a_src[row * 2 + head] = ps[r];
        a_dst[row * 2 + head] = pd[r];
      }
    }
  }
}

// ---------------- K1: zero (line-padded) bucket counters ----------------
__global__ void zeroB(int* __restrict__ a, int n) {
  int i = blockIdx.x * blockDim.x + threadIdx.x;
  if (i < n) a[i] = 0;
}

// ---------------- K1b: Wc1 fp32 -> bf16 MFMA B-fragment order (once) -------
// frag idx = (t*8+n)*64 + l; elems j=0..7 -> B[t*32 + (l>>4)*8 + j][n*16+(l&15)]
__global__ void wc1_swz(const float* __restrict__ Wc1,
                        unsigned short* __restrict__ wsw) {
  int idx = blockIdx.x * blockDim.x + threadIdx.x;
  if (idx >= 12 * 8 * 64) return;
  int l = idx & 63;
  int n = (idx >> 6) & 7;
  int t = idx >> 9;
  int col = n * 16 + (l & 15);
  int kbase = t * 32 + (l >> 4) * 8;
  uint4 o;
  o.x = pack2bf(Wc1[(kbase + 0) * 128 + col], Wc1[(kbase + 1) * 128 + col]);
  o.y = pack2bf(Wc1[(kbase + 2) * 128 + col], Wc1[(kbase + 3) * 128 + col]);
  o.z = pack2bf(Wc1[(kbase + 4) * 128 + col], Wc1[(kbase + 5) * 128 + col]);
  o.w = pack2bf(Wc1[(kbase + 6) * 128 + col], Wc1[(kbase + 7) * 128 + col]);
  *(uint4*)(wsw + (size_t)idx * 8) = o;
}

// ---------------- K2: LDS radix-partition edge scatter ----------------
__global__ __launch_bounds__(512) void scatter_p(
    const int* __restrict__ ei0, const int* __restrict__ ei1,
    const int* __restrict__ ei2, int E0, int E1, int E2,
    int nbpc, int* __restrict__ bktCnt, int* __restrict__ bkt) {
  __shared__ int hist[NBINS_PAD];
  __shared__ int binStart[NBINS_PAD];
  __shared__ int binResv[NBINS_PAD];
  __shared__ int fillB[NBINS_PAD];
  __shared__ int scanBuf[SBS];
  __shared__ int stage[STB];
  __shared__ int gdst[STB];
  const int tid = threadIdx.x;
  const int slice = blockIdx.x & (SLICES - 1);   // ~= XCD id (round-robin)
  const int nbins = 3 * nbpc;
  const int c1 = E0, c2 = E0 + E1, totE = c2 + E2;
  const int eb = blockIdx.x * STB;

  for (int b = tid; b < NBINS_PAD; b += SBS) hist[b] = 0;
  __syncthreads();

  // load 16 edges/thread, histogram bins
  int binv[SEPT], payv[SEPT];
#pragma unroll
  for (int k = 0; k < SEPT; ++k) {
    int g = eb + k * SBS + tid;
    int bn = -1, pay = 0;
    if (g < totE) {
      int s, d, cat;
      if (g < c1)      { s = ei0[g]; d = ei0[E0 + g]; cat = 0; }
      else if (g < c2) { int t = g - c1; s = ei1[t]; d = ei1[E1 + t]; cat = 1; }
      else             { int t = g - c2; s = ei2[t]; d = ei2[E2 + t]; cat = 2; }
      bn = cat * nbpc + (d >> 7);
      pay = ((d & 127) << 16) | s;
      atomicAdd(&hist[bn], 1);
    }
    binv[k] = bn; payv[k] = pay;
  }
  __syncthreads();

  // exclusive scan of hist -> binStart (2 bins/thread, Hillis-Steele on 512)
  const int a0 = hist[tid * 2], a1 = hist[tid * 2 + 1];
  scanBuf[tid] = a0 + a1;
  __syncthreads();
  for (int off = 1; off < SBS; off <<= 1) {
    int v = (tid >= off) ? scanBuf[tid - off] : 0;
    __syncthreads();
    scanBuf[tid] += v;
    __syncthreads();
  }
  const int total = scanBuf[SBS - 1];
  const int base = (tid > 0) ? scanBuf[tid - 1] : 0;
  binStart[tid * 2] = base;
  binStart[tid * 2 + 1] = base + a0;

  // reserve a contiguous run per non-empty bin (XCD-private slice counters)
  for (int b = tid; b < NBINS_PAD; b += SBS) {
    fillB[b] = 0;
    int c = hist[b];
    if (c > 0 && b < nbins)
      binResv[b] = atomicAdd(&bktCnt[(b * SLICES + slice) * 16], c);
  }
  __syncthreads();

  // counting-sort edges into LDS stage, record global destination
#pragma unroll
  for (int k = 0; k < SEPT; ++k) {
    int bn = binv[k];
    if (bn >= 0) {
      int f = atomicAdd(&fillB[bn], 1);
      int p = binStart[bn] + f;
      int go = binResv[bn] + f;
      stage[p] = payv[k];
      gdst[p] = (go < CAPX) ? ((bn * SLICES + slice) * CAPX + go) : -1;
    }
  }
  __syncthreads();

  // run-ordered write-out: consecutive lanes -> consecutive addresses
  for (int i = tid; i < total; i += SBS) {
    int g = gdst[i];
    if (g >= 0) bkt[g] = stage[i];
  }
}

// ---------------- K3: merge slices, LDS counting sort, compact in place -----
// Self-loops injected analytically: cntA init = 1, self-loop src at slot
// scanA[t]-1 (edges fill relative slots 0..cntA-2 via fillA).
__global__ __launch_bounds__(256) void sortbkt(
    int* __restrict__ bkt, const int* __restrict__ bktCnt,
    int2* __restrict__ offcnt, int Nn, int nbpc) {
  __shared__ int cntA[128], scanA[128], fillA[128];
  __shared__ int esort[BCAP];
  const int tid = threadIdx.x;
  const int b = blockIdx.x;
  const int cat = b / nbpc, bl = b - cat * nbpc, dBase = bl << 7;
  if (tid < 128) {
    cntA[tid] = (dBase + tid < Nn) ? 1 : 0;   // self-loop
    fillA[tid] = 0;
  }
  __syncthreads();
  int ns[SLICES];
#pragma unroll
  for (int s = 0; s < SLICES; ++s)
    ns[s] = min(bktCnt[(b * SLICES + s) * 16], CAPX);
  // pass 1: histogram by dLow
#pragma unroll
  for (int s = 0; s < SLICES; ++s) {
    const int* seg = bkt + (size_t)(b * SLICES + s) * CAPX;
    for (int i = tid; i < ns[s]; i += 256) atomicAdd(&cntA[seg[i] >> 16], 1);
  }
  __syncthreads();
  if (tid < 128) scanA[tid] = cntA[tid];
  __syncthreads();
  for (int off = 1; off < 128; off <<= 1) {
    int t = (tid < 128 && tid >= off) ? scanA[tid - off] : 0;
    __syncthreads();
    if (tid < 128) scanA[tid] += t;
    __syncthreads();
  }
  // pass 2: place edges (exclusive start for node t = scanA[t]-cntA[t])
#pragma unroll
  for (int s = 0; s < SLICES; ++s) {
    const int* seg = bkt + (size_t)(b * SLICES + s) * CAPX;
    for (int i = tid; i < ns[s]; i += 256) {
      int v = seg[i];
      int n = v >> 16;
      int p = scanA[n] - cntA[n] + atomicAdd(&fillA[n], 1);
      esort[p] = v & 0xFFFF;
    }
  }
  // self-loop: last slot of node's segment
  if (tid < 128 && dBase + tid < Nn) esort[scanA[tid] - 1] = dBase + tid;
  __syncthreads();
  const int tot = scanA[127];
  int* outp = bkt + (size_t)b * BCAP;     // compact to bucket base
  for (int i = tid; i < tot; i += 256) outp[i] = esort[i];
  if (tid < 128 && dBase + tid < Nn)
    offcnt[(size_t)cat * Nn + dBase + tid] =
        make_int2(b * BCAP + scanA[tid] - cntA[tid], cntA[tid]);
}

// ---------------- K5: softmax + bf16x2 gather -> ah bf16 (elu+bias fused) ---
// Phase 2: lane l accumulates cols (2l, 2l+1); head weight lane<32 -> head0.
// Both head weights broadcast UNCONDITIONALLY then selected (gfx950 bpermute
// from EXEC-inactive source returns 0 -> no __shfl in divergent flow).
// Output: ahc[node*384 .. ] = bf16(elu(acc + bias[col])) (A of the MLP GEMM).
__global__ __launch_bounds__(256) void aggregate(
    const unsigned short* __restrict__ xwh, const float* __restrict__ a_src,
    const float* __restrict__ a_dst, const int2* __restrict__ offcnt,
    const int* __restrict__ adjS, const float* __restrict__ bias,
    unsigned short* __restrict__ ahc, int Nn) {
  const int node = (int)((blockIdx.x * (size_t)blockDim.x + threadIdx.x) >> 6);
  const int lane = threadIdx.x & 63;
  if (node >= Nn) return;
  const int2 oc = offcnt[node];
  const int base = oc.x, end = oc.x + oc.y;
  const float2 ad = ((const float2*)a_dst)[node];

  // phase 1: lane-strided online softmax stats; keep first chunk in regs
  float m0 = -1e30f, s0 = 0.f, m1 = -1e30f, s1 = 0.f;
  int sv0 = 0; float ex0 = -1e30f, ey0 = -1e30f;
  for (int cb = base; cb < end; cb += 64) {
    int j = cb + lane;
    int sv = 0; float ex = -1e30f, ey = -1e30f;
    if (j < end) {
      sv = adjS[j];
      float2 as = ((const float2*)a_src)[sv];
      ex = lrelu02(as.x + ad.x);
      ey = lrelu02(as.y + ad.y);
      float nm0 = fmaxf(m0, ex);
      s0 = s0 * __expf(m0 - nm0) + __expf(ex - nm0); m0 = nm0;
      float nm1 = fmaxf(m1, ey);
      s1 = s1 * __expf(m1 - nm1) + __expf(ey - nm1); m1 = nm1;
    }
    if (cb == base) { sv0 = sv; ex0 = ex; ey0 = ey; }
  }
#pragma unroll
  for (int off = 32; off; off >>= 1) {
    float om0 = __shfl_xor(m0, off), os0 = __shfl_xor(s0, off);
    float nm0 = fmaxf(m0, om0);
    s0 = s0 * __expf(m0 - nm0) + os0 * __expf(om0 - nm0); m0 = nm0;
    float om1 = __shfl_xor(m1, off), os1 = __shfl_xor(s1, off);
    float nm1 = fmaxf(m1, om1);
    s1 = s1 * __expf(m1 - nm1) + os1 * __expf(om1 - nm1); m1 = nm1;
  }
  const float inv0 = 1.f / s0, inv1 = 1.f / s1;
  const bool h0 = (lane < 32);   // this lane's cols (2l,2l+1): head0 if l<32

  // phase 2: weight once per edge (its lane), shfl-broadcast, bf16x2 gather x4
  float2 acc = {0.f, 0.f};
  for (int cb = base; cb < end; cb += 64) {
    const int cnt = min(64, end - cb);
    int srcv; float w0v, w1v;
    if (cb == base) {
      srcv = sv0;
      w0v = __expf(ex0 - m0) * inv0;   // inactive lanes: exp(-inf)=0
      w1v = __expf(ey0 - m1) * inv1;
    } else {
      srcv = 0; float ex = -1e30f, ey = -1e30f;
      if (lane < cnt) {
        srcv = adjS[cb + lane];
        float2 as = ((const float2*)a_src)[srcv];
        ex = lrelu02(as.x + ad.x);
        ey = lrelu02(as.y + ad.y);
      }
      w0v = __expf(ex - m0) * inv0;
      w1v = __expf(ey - m1) * inv1;
    }
    int k = 0;
    for (; k + 4 <= cnt; k += 4) {
      int sa = __shfl(srcv, k),     sb = __shfl(srcv, k + 1);
      int sc = __shfl(srcv, k + 2), sd = __shfl(srcv, k + 3);
      unsigned ua = ((const unsigned*)(xwh + (size_t)sa * 128))[lane];
      unsigned ub = ((const unsigned*)(xwh + (size_t)sb * 128))[lane];
      unsigned uc = ((const unsigned*)(xwh + (size_t)sc * 128))[lane];
      unsigned ud = ((const unsigned*)(xwh + (size_t)sd * 128))[lane];
      // convergent: both heads' weights broadcast at full exec, then select
      float w0a = __shfl(w0v, k),     w1a = __shfl(w1v, k);
      float w0b = __shfl(w0v, k + 1), w1b = __shfl(w1v, k + 1);
      float w0c = __shfl(w0v, k + 2), w1c = __shfl(w1v, k + 2);
      float w0d = __shfl(w0v, k + 3), w1d = __shfl(w1v, k + 3);
      float wa = h0 ? w0a : w1a;
      float wb = h0 ? w0b : w1b;
      float wc = h0 ? w0c : w1c;
      float wd = h0 ? w0d : w1d;
      acc.x = fmaf(wa, bflo2f(ua), acc.x); acc.y = fmaf(wa, bfhi2f(ua), acc.y);
      acc.x = fmaf(wb, bflo2f(ub), acc.x); acc.y = fmaf(wb, bfhi2f(ub), acc.y);
      acc.x = fmaf(wc, bflo2f(uc), acc.x); acc.y = fmaf(wc, bfhi2f(uc), acc.y);
      acc.x = fmaf(wd, bflo2f(ud), acc.x); acc.y = fmaf(wd, bfhi2f(ud), acc.y);
    }
    for (; k < cnt; ++k) {
      int s = __shfl(srcv, k);
      float w0b_ = __shfl(w0v, k), w1b_ = __shfl(w1v, k);
      float w = h0 ? w0b_ : w1b_;
      unsigned u = ((const unsigned*)(xwh + (size_t)s * 128))[lane];
      acc.x = fmaf(w, bflo2f(u), acc.x);
      acc.y = fmaf(w, bfhi2f(u), acc.y);
    }
  }
  const float2 bv = ((const float2*)bias)[lane];
  ((unsigned*)(ahc + (size_t)node * 384))[lane] =
      pack2bf(elu1(acc.x + bv.x), elu1(acc.y + bv.y));
}

// ---------------- K6: MFMA MLP: ah[N,384](bf16) @ wc1(bf16) + epilogue ------
// 4 waves/block; wave = 16 rows x 128 cols = 8 acc tiles of 16x16; K=384 in
// 12 steps of 32. A-frags from global (each row read once); B-frags from
// L2-hot pre-swizzled wsw. No LDS, no barriers.
__global__ __launch_bounds__(256) void final_mlp_mfma(
    const unsigned short* __restrict__ ah, const unsigned short* __restrict__ wsw,
    const float* __restrict__ bc1, const float* __restrict__ Wc2,
    const float* __restrict__ bc2, float* __restrict__ out, int Nn) {
  const int tid = threadIdx.x;
  const int l = tid & 63;
  const int w = tid >> 6;
  const int lrow = l & 15;        // A row in tile / D col
  const int lk = (l >> 4) * 8;    // k-offset in 32-chunk
  int row = blockIdx.x * 64 + w * 16 + lrow;
  int arow = row < Nn ? row : Nn - 1;
  const unsigned short* aptr = ah + (size_t)arow * 384 + lk;
  const unsigned short* bptr = wsw + (size_t)l * 8;

  f32x4 acc[8];
#pragma unroll
  for (int n = 0; n < 8; ++n) acc[n] = (f32x4){0.f, 0.f, 0.f, 0.f};

  for (int t = 0; t < 12; ++t) {
    uint4 av = *(const uint4*)(aptr + t * 32);
    short8 af = __builtin_bit_cast(short8, av);
#pragma unroll
    for (int n = 0; n < 8; ++n) {
      uint4 bv = *(const uint4*)(bptr + (size_t)(t * 8 + n) * 512);
      short8 bf = __builtin_bit_cast(short8, bv);
      acc[n] = __builtin_amdgcn_mfma_f32_16x16x32_bf16(af, bf, acc[n], 0, 0, 0);
    }
  }

  // epilogue: h = relu(acc + bc1[col]); out_row = sum_col h*Wc2[col] + bc2
  float bcv[8], w2v[8];
#pragma unroll
  for (int n = 0; n < 8; ++n) {
    int col = n * 16 + lrow;
    bcv[n] = bc1[col];
    w2v[n] = Wc2[col];
  }
  float p[4];
#pragma unroll
  for (int r = 0; r < 4; ++r) {
    float s = 0.f;
#pragma unroll
    for (int n = 0; n < 8; ++n)
      s = fmaf(fmaxf(acc[n][r] + bcv[n], 0.f), w2v[n], s);
#pragma unroll
    for (int off = 1; off < 16; off <<= 1) s += __shfl_xor(s, off);
    p[r] = s;
  }
  if (lrow == 0) {
    int orow = blockIdx.x * 64 + w * 16 + (l >> 4) * 4;
    float b2 = bc2[0];
    if (orow + 3 < Nn) {
      float4 o = {p[0] + b2, p[1] + b2, p[2] + b2, p[3] + b2};
      *(float4*)(out + orow) = o;
    } else {
#pragma unroll
      for (int r = 0; r < 4; ++r)
        if (orow + r < Nn) out[orow + r] = p[r] + b2;
    }
  }
}

// ---------------------------------------------------------------------------
extern "C" void kernel_launch(void* const* d_in, const int* in_sizes, int n_in,
                              void* d_out, int out_size, void* d_ws, size_t ws_size,
                              hipStream_t stream) {
  const int Nn = out_size;            // 40000
  const int E0 = in_sizes[1] / 2;
  const int E1 = in_sizes[7] / 2;
  const int E2 = in_sizes[13] / 2;
  const int totE = E0 + E1 + E2;
  const int Nt = 3 * Nn;
  const int nbpc = (Nn + 127) / 128;  // buckets per category (313)
  const int NB = 3 * nbpc;            // 939

  char* base = (char*)d_ws;
  size_t off = 0;
  auto carve = [&](size_t bytes) -> void* {
    off = (off + 255) & ~(size_t)255;
    void* p = base + off;
    off += bytes;
    return p;
  };
  unsigned short* xwh = (unsigned short*)carve((size_t)Nn * 128 * 2); // bf16
  unsigned short* ah  = (unsigned short*)carve((size_t)Nn * 384 * 2); // bf16 A
  unsigned short* wsw = (unsigned short*)carve((size_t)12 * 8 * 64 * 8 * 2);
  float* a_src3 = (float*)carve((size_t)Nt * 2 * 4);
  float* a_dst3 = (float*)carve((size_t)Nt * 2 * 4);
  int*  bktCnt  = (int*)carve((size_t)NB * SLICES * 16 * 4); // line-padded
  int2* offcnt3 = (int2*)carve((size_t)Nt * 8);
  int*  bkt     = (int*)carve((size_t)NB * BCAP * 4);
  (void)ws_size; (void)n_in;

  const int* ei0 = (const int*)d_in[1];
  const int* ei1 = (const int*)d_in[7];
  const int* ei2 = (const int*)d_in[13];

  // bucketed adjacency build + one-shot Wc1 swizzle
  const int ncnt = NB * SLICES * 16;
  zeroB<<<(ncnt + 255) / 256, 256, 0, stream>>>(bktCnt, ncnt);
  wc1_swz<<<(12 * 8 * 64 + 255) / 256, 256, 0, stream>>>(
      (const float*)d_in[18], wsw);
  scatter_p<<<(totE + STB - 1) / STB, SBS, 0, stream>>>(
      ei0, ei1, ei2, E0, E1, E2, nbpc, bktCnt, bkt);
  sortbkt<<<NB, 256, 0, stream>>>(bkt, bktCnt, offcnt3, Nn, nbpc);

  for (int cat = 0; cat < 3; ++cat) {
    const float* x   = (const float*)d_in[6 * cat + 0];
    const float* W   = (const float*)d_in[6 * cat + 2];
    const float* ats = (const float*)d_in[6 * cat + 3];
    const float* atd = (const float*)d_in[6 * cat + 4];
    const float* bia = (const float*)d_in[6 * cat + 5];
    const int K = in_sizes[6 * cat] / Nn;
    float* a_src_c = a_src3 + (size_t)cat * Nn * 2;
    float* a_dst_c = a_dst3 + (size_t)cat * Nn * 2;

    gemm_att<<<(Nn + TM - 1) / TM, 256, 0, stream>>>(
        x, W, ats, atd, xwh, a_src_c, a_dst_c, Nn, K);
    aggregate<<<((size_t)Nn * 64 + 255) / 256, 256, 0, stream>>>(
        xwh, a_src_c, a_dst_c, offcnt3 + (size_t)cat * Nn, bkt, bia,
        ah + (size_t)cat * 128, Nn);
  }

  final_mlp_mfma<<<(Nn + 63) / 64, 256, 0, stream>>>(
      ah, wsw, (const float*)d_in[19], (const float*)d_in[20],
      (const float*)d_in[21], (float*)d_out, Nn);
}

// Round 9
// 323.480 us; speedup vs baseline: 1.3298x; 1.0782x over previous
//
#include <hip/hip_runtime.h>
#include <cstdint>
#include <cstddef>

// ---------------------------------------------------------------------------
// FCAGAT: 3x GATConv (H=2, C=64) + ELU + concat + MLP(384->128->1)
// R8: scatter_p LDS radix-partition. R9/R10: fp32 GEMM restructures dead end
// (~45% VALU eff floor). R11/R12: __shfl must stay OUT of divergent control
// flow (inactive-source bpermute returns 0 on gfx950). R13: bf16 xw gather.
// R14: final_mlp -> MFMA bf16 (398->349us; fragment layouts harness-verified).
// R15: gemm_att -> same MFMA structure. A-side packs fp32->bf16 in-register
// (16 rows x 128B contiguous per K-step: coalescing-clean); B = per-cat
// pre-swizzled bf16 W (w_swz, L2-hot). Attention dots fused in D-fragment
// epilogue: per-thread dots over 8 cols, 16-lane shfl_xor reduce (full exec),
// lane-0 float2 store. aggregate untouched this round (next: fp16-packed
// weight shfl).
//   K1 zeroB        : bktCnt = 0
//   K1b w_swz       : W fp32 -> bf16 MFMA B-fragment order (Wc1 + 3x Wcat)
//   K2 scatter_p    : LDS-partitioned edge scatter -> (bucket,slice) runs
//   K3 sortbkt      : merge slices, LDS counting sort + self-loop inject
//   K4 gemm_att_mfma: xw(bf16) = x@W via MFMA + fused att dots in epilogue
//   K5 aggregate    : wave/node softmax + bf16x2 gather -> ah bf16 elu'd
//   K6 final_mlp_mfma: ah[N,384](bf16) @ Wc1(bf16) MFMA + relu/Wc2 epilogue
// ---------------------------------------------------------------------------

__device__ __forceinline__ float lrelu02(float x) { return x > 0.f ? x : 0.2f * x; }
__device__ __forceinline__ float elu1(float x) { return x > 0.f ? x : (__expf(x) - 1.f); }

// bf16 pack/unpack (RNE; no NaN in this data)
__device__ __forceinline__ unsigned bfrne(float x) {
  unsigned u = __float_as_uint(x);
  return (u + 0x7FFFu + ((u >> 16) & 1u)) >> 16;
}
__device__ __forceinline__ unsigned pack2bf(float lo, float hi) {
  return bfrne(lo) | (bfrne(hi) << 16);
}
__device__ __forceinline__ float bflo2f(unsigned u) { return __uint_as_float(u << 16); }
__device__ __forceinline__ float bfhi2f(unsigned u) { return __uint_as_float(u & 0xFFFF0000u); }

typedef __attribute__((ext_vector_type(8))) short short8;
typedef __attribute__((ext_vector_type(4))) float f32x4;

#define SLICES 8
#define CAPX 448               // per-(bucket,slice): mean ~240, +13 sigma
#define BCAP (SLICES * CAPX)   // 3584 >= max bucket total (~2046)

#define SBS 512                // scatter block threads
#define SEPT 16                // edges per thread
#define STB (SBS * SEPT)       // 8192 edges per block
#define NBINS_PAD 1024         // >= 3*nbpc = 939, padded pow2

// ---------------- K1: zero (line-padded) bucket counters ----------------
__global__ void zeroB(int* __restrict__ a, int n) {
  int i = blockIdx.x * blockDim.x + threadIdx.x;
  if (i < n) a[i] = 0;
}

// ---------------- K1b: W fp32 -> bf16 MFMA B-fragment order (once) ---------
// frag idx = (t*8+n)*64 + l; elems j=0..7 -> W[t*32 + (l>>4)*8 + j][n*16+(l&15)]
__global__ void w_swz(const float* __restrict__ W,
                      unsigned short* __restrict__ wsw, int nt) {
  int idx = blockIdx.x * blockDim.x + threadIdx.x;
  if (idx >= nt * 8 * 64) return;
  int l = idx & 63;
  int n = (idx >> 6) & 7;
  int t = idx >> 9;
  int col = n * 16 + (l & 15);
  int kbase = t * 32 + (l >> 4) * 8;
  uint4 o;
  o.x = pack2bf(W[(kbase + 0) * 128 + col], W[(kbase + 1) * 128 + col]);
  o.y = pack2bf(W[(kbase + 2) * 128 + col], W[(kbase + 3) * 128 + col]);
  o.z = pack2bf(W[(kbase + 4) * 128 + col], W[(kbase + 5) * 128 + col]);
  o.w = pack2bf(W[(kbase + 6) * 128 + col], W[(kbase + 7) * 128 + col]);
  *(uint4*)(wsw + (size_t)idx * 8) = o;
}

// ---------------- K4: MFMA xw(bf16) = x@W + fused attention dots ------------
// 4 waves/block; wave = 16 rows x 128 cols; K in nt steps of 32. A packed
// fp32->bf16 in-register; B from L2-hot pre-swizzled wsw. No LDS/barriers.
// Layouts (harness-verified in R14): A row=l&15, k=(l>>4)*8+j;
// B k=(l>>4)*8+j, col=n*16+(l&15); D col=l&15, row=(l>>4)*4+r.
__global__ __launch_bounds__(256) void gemm_att_mfma(
    const float* __restrict__ X, const unsigned short* __restrict__ wsw,
    const float* __restrict__ att_s, const float* __restrict__ att_d,
    unsigned short* __restrict__ XWH, float* __restrict__ a_src,
    float* __restrict__ a_dst, int M, int K) {
  const int tid = threadIdx.x;
  const int l = tid & 63;
  const int w = tid >> 6;
  const int lrow = l & 15;
  const int lk = (l >> 4) * 8;
  const int row0 = blockIdx.x * 64 + w * 16;
  int arow = row0 + lrow; if (arow >= M) arow = M - 1;
  const float* aptr = X + (size_t)arow * K + lk;
  const unsigned short* bptr = wsw + (size_t)l * 8;
  const int nt = K >> 5;

  f32x4 acc[8];
#pragma unroll
  for (int n = 0; n < 8; ++n) acc[n] = (f32x4){0.f, 0.f, 0.f, 0.f};

  for (int t = 0; t < nt; ++t) {
    float4 xa = *(const float4*)(aptr + t * 32);
    float4 xb = *(const float4*)(aptr + t * 32 + 4);
    uint4 av;
    av.x = pack2bf(xa.x, xa.y);
    av.y = pack2bf(xa.z, xa.w);
    av.z = pack2bf(xb.x, xb.y);
    av.w = pack2bf(xb.z, xb.w);
    short8 af = __builtin_bit_cast(short8, av);
#pragma unroll
    for (int n = 0; n < 8; ++n) {
      uint4 bv = *(const uint4*)(bptr + (size_t)(t * 8 + n) * 512);
      short8 bf = __builtin_bit_cast(short8, bv);
      acc[n] = __builtin_amdgcn_mfma_f32_16x16x32_bf16(af, bf, acc[n], 0, 0, 0);
    }
  }

  // epilogue: store xw bf16 + attention dots (head0 = n<4, head1 = n>=4)
  float as_[8], ad_[8];
#pragma unroll
  for (int n = 0; n < 8; ++n) {
    int col = n * 16 + lrow;
    as_[n] = att_s[col];
    ad_[n] = att_d[col];
  }
#pragma unroll
  for (int r = 0; r < 4; ++r) {
    int wrow = row0 + (l >> 4) * 4 + r;
    const bool ok = wrow < M;
    float ps0 = 0.f, ps1 = 0.f, pd0 = 0.f, pd1 = 0.f;
#pragma unroll
    for (int n = 0; n < 8; ++n) {
      float v = acc[n][r];
      if (ok) XWH[(size_t)wrow * 128 + n * 16 + lrow] = (unsigned short)bfrne(v);
      if (n < 4) { ps0 = fmaf(v, as_[n], ps0); pd0 = fmaf(v, ad_[n], pd0); }
      else       { ps1 = fmaf(v, as_[n], ps1); pd1 = fmaf(v, ad_[n], pd1); }
    }
    // convergent 16-lane reduce (full exec; stores above are predicated only)
#pragma unroll
    for (int off = 1; off < 16; off <<= 1) {
      ps0 += __shfl_xor(ps0, off); ps1 += __shfl_xor(ps1, off);
      pd0 += __shfl_xor(pd0, off); pd1 += __shfl_xor(pd1, off);
    }
    if (lrow == 0 && ok) {
      ((float2*)a_src)[wrow] = make_float2(ps0, ps1);
      ((float2*)a_dst)[wrow] = make_float2(pd0, pd1);
    }
  }
}

// ---------------- K2: LDS radix-partition edge scatter ----------------
__global__ __launch_bounds__(512) void scatter_p(
    const int* __restrict__ ei0, const int* __restrict__ ei1,
    const int* __restrict__ ei2, int E0, int E1, int E2,
    int nbpc, int* __restrict__ bktCnt, int* __restrict__ bkt) {
  __shared__ int hist[NBINS_PAD];
  __shared__ int binStart[NBINS_PAD];
  __shared__ int binResv[NBINS_PAD];
  __shared__ int fillB[NBINS_PAD];
  __shared__ int scanBuf[SBS];
  __shared__ int stage[STB];
  __shared__ int gdst[STB];
  const int tid = threadIdx.x;
  const int slice = blockIdx.x & (SLICES - 1);   // ~= XCD id (round-robin)
  const int nbins = 3 * nbpc;
  const int c1 = E0, c2 = E0 + E1, totE = c2 + E2;
  const int eb = blockIdx.x * STB;

  for (int b = tid; b < NBINS_PAD; b += SBS) hist[b] = 0;
  __syncthreads();

  // load 16 edges/thread, histogram bins
  int binv[SEPT], payv[SEPT];
#pragma unroll
  for (int k = 0; k < SEPT; ++k) {
    int g = eb + k * SBS + tid;
    int bn = -1, pay = 0;
    if (g < totE) {
      int s, d, cat;
      if (g < c1)      { s = ei0[g]; d = ei0[E0 + g]; cat = 0; }
      else if (g < c2) { int t = g - c1; s = ei1[t]; d = ei1[E1 + t]; cat = 1; }
      else             { int t = g - c2; s = ei2[t]; d = ei2[E2 + t]; cat = 2; }
      bn = cat * nbpc + (d >> 7);
      pay = ((d & 127) << 16) | s;
      atomicAdd(&hist[bn], 1);
    }
    binv[k] = bn; payv[k] = pay;
  }
  __syncthreads();

  // exclusive scan of hist -> binStart (2 bins/thread, Hillis-Steele on 512)
  const int a0 = hist[tid * 2], a1 = hist[tid * 2 + 1];
  scanBuf[tid] = a0 + a1;
  __syncthreads();
  for (int off = 1; off < SBS; off <<= 1) {
    int v = (tid >= off) ? scanBuf[tid - off] : 0;
    __syncthreads();
    scanBuf[tid] += v;
    __syncthreads();
  }
  const int total = scanBuf[SBS - 1];
  const int base = (tid > 0) ? scanBuf[tid - 1] : 0;
  binStart[tid * 2] = base;
  binStart[tid * 2 + 1] = base + a0;

  // reserve a contiguous run per non-empty bin (XCD-private slice counters)
  for (int b = tid; b < NBINS_PAD; b += SBS) {
    fillB[b] = 0;
    int c = hist[b];
    if (c > 0 && b < nbins)
      binResv[b] = atomicAdd(&bktCnt[(b * SLICES + slice) * 16], c);
  }
  __syncthreads();

  // counting-sort edges into LDS stage, record global destination
#pragma unroll
  for (int k = 0; k < SEPT; ++k) {
    int bn = binv[k];
    if (bn >= 0) {
      int f = atomicAdd(&fillB[bn], 1);
      int p = binStart[bn] + f;
      int go = binResv[bn] + f;
      stage[p] = payv[k];
      gdst[p] = (go < CAPX) ? ((bn * SLICES + slice) * CAPX + go) : -1;
    }
  }
  __syncthreads();

  // run-ordered write-out: consecutive lanes -> consecutive addresses
  for (int i = tid; i < total; i += SBS) {
    int g = gdst[i];
    if (g >= 0) bkt[g] = stage[i];
  }
}

// ---------------- K3: merge slices, LDS counting sort, compact in place -----
// Self-loops injected analytically: cntA init = 1, self-loop src at slot
// scanA[t]-1 (edges fill relative slots 0..cntA-2 via fillA).
__global__ __launch_bounds__(256) void sortbkt(
    int* __restrict__ bkt, const int* __restrict__ bktCnt,
    int2* __restrict__ offcnt, int Nn, int nbpc) {
  __shared__ int cntA[128], scanA[128], fillA[128];
  __shared__ int esort[BCAP];
  const int tid = threadIdx.x;
  const int b = blockIdx.x;
  const int cat = b / nbpc, bl = b - cat * nbpc, dBase = bl << 7;
  if (tid < 128) {
    cntA[tid] = (dBase + tid < Nn) ? 1 : 0;   // self-loop
    fillA[tid] = 0;
  }
  __syncthreads();
  int ns[SLICES];
#pragma unroll
  for (int s = 0; s < SLICES; ++s)
    ns[s] = min(bktCnt[(b * SLICES + s) * 16], CAPX);
  // pass 1: histogram by dLow
#pragma unroll
  for (int s = 0; s < SLICES; ++s) {
    const int* seg = bkt + (size_t)(b * SLICES + s) * CAPX;
    for (int i = tid; i < ns[s]; i += 256) atomicAdd(&cntA[seg[i] >> 16], 1);
  }
  __syncthreads();
  if (tid < 128) scanA[tid] = cntA[tid];
  __syncthreads();
  for (int off = 1; off < 128; off <<= 1) {
    int t = (tid < 128 && tid >= off) ? scanA[tid - off] : 0;
    __syncthreads();
    if (tid < 128) scanA[tid] += t;
    __syncthreads();
  }
  // pass 2: place edges (exclusive start for node t = scanA[t]-cntA[t])
#pragma unroll
  for (int s = 0; s < SLICES; ++s) {
    const int* seg = bkt + (size_t)(b * SLICES + s) * CAPX;
    for (int i = tid; i < ns[s]; i += 256) {
      int v = seg[i];
      int n = v >> 16;
      int p = scanA[n] - cntA[n] + atomicAdd(&fillA[n], 1);
      esort[p] = v & 0xFFFF;
    }
  }
  // self-loop: last slot of node's segment
  if (tid < 128 && dBase + tid < Nn) esort[scanA[tid] - 1] = dBase + tid;
  __syncthreads();
  const int tot = scanA[127];
  int* outp = bkt + (size_t)b * BCAP;     // compact to bucket base
  for (int i = tid; i < tot; i += 256) outp[i] = esort[i];
  if (tid < 128 && dBase + tid < Nn)
    offcnt[(size_t)cat * Nn + dBase + tid] =
        make_int2(b * BCAP + scanA[tid] - cntA[tid], cntA[tid]);
}

// ---------------- K5: softmax + bf16x2 gather -> ah bf16 (elu+bias fused) ---
// Phase 2: lane l accumulates cols (2l, 2l+1); head weight lane<32 -> head0.
// Both head weights broadcast UNCONDITIONALLY then selected (gfx950 bpermute
// from EXEC-inactive source returns 0 -> no __shfl in divergent flow).
// Output: ahc[node*384 .. ] = bf16(elu(acc + bias[col])) (A of the MLP GEMM).
__global__ __launch_bounds__(256) void aggregate(
    const unsigned short* __restrict__ xwh, const float* __restrict__ a_src,
    const float* __restrict__ a_dst, const int2* __restrict__ offcnt,
    const int* __restrict__ adjS, const float* __restrict__ bias,
    unsigned short* __restrict__ ahc, int Nn) {
  const int node = (int)((blockIdx.x * (size_t)blockDim.x + threadIdx.x) >> 6);
  const int lane = threadIdx.x & 63;
  if (node >= Nn) return;
  const int2 oc = offcnt[node];
  const int base = oc.x, end = oc.x + oc.y;
  const float2 ad = ((const float2*)a_dst)[node];

  // phase 1: lane-strided online softmax stats; keep first chunk in regs
  float m0 = -1e30f, s0 = 0.f, m1 = -1e30f, s1 = 0.f;
  int sv0 = 0; float ex0 = -1e30f, ey0 = -1e30f;
  for (int cb = base; cb < end; cb += 64) {
    int j = cb + lane;
    int sv = 0; float ex = -1e30f, ey = -1e30f;
    if (j < end) {
      sv = adjS[j];
      float2 as = ((const float2*)a_src)[sv];
      ex = lrelu02(as.x + ad.x);
      ey = lrelu02(as.y + ad.y);
      float nm0 = fmaxf(m0, ex);
      s0 = s0 * __expf(m0 - nm0) + __expf(ex - nm0); m0 = nm0;
      float nm1 = fmaxf(m1, ey);
      s1 = s1 * __expf(m1 - nm1) + __expf(ey - nm1); m1 = nm1;
    }
    if (cb == base) { sv0 = sv; ex0 = ex; ey0 = ey; }
  }
#pragma unroll
  for (int off = 32; off; off >>= 1) {
    float om0 = __shfl_xor(m0, off), os0 = __shfl_xor(s0, off);
    float nm0 = fmaxf(m0, om0);
    s0 = s0 * __expf(m0 - nm0) + os0 * __expf(om0 - nm0); m0 = nm0;
    float om1 = __shfl_xor(m1, off), os1 = __shfl_xor(s1, off);
    float nm1 = fmaxf(m1, om1);
    s1 = s1 * __expf(m1 - nm1) + os1 * __expf(om1 - nm1); m1 = nm1;
  }
  const float inv0 = 1.f / s0, inv1 = 1.f / s1;
  const bool h0 = (lane < 32);   // this lane's cols (2l,2l+1): head0 if l<32

  // phase 2: weight once per edge (its lane), shfl-broadcast, bf16x2 gather x4
  float2 acc = {0.f, 0.f};
  for (int cb = base; cb < end; cb += 64) {
    const int cnt = min(64, end - cb);
    int srcv; float w0v, w1v;
    if (cb == base) {
      srcv = sv0;
      w0v = __expf(ex0 - m0) * inv0;   // inactive lanes: exp(-inf)=0
      w1v = __expf(ey0 - m1) * inv1;
    } else {
      srcv = 0; float ex = -1e30f, ey = -1e30f;
      if (lane < cnt) {
        srcv = adjS[cb + lane];
        float2 as = ((const float2*)a_src)[srcv];
        ex = lrelu02(as.x + ad.x);
        ey = lrelu02(as.y + ad.y);
      }
      w0v = __expf(ex - m0) * inv0;
      w1v = __expf(ey - m1) * inv1;
    }
    int k = 0;
    for (; k + 4 <= cnt; k += 4) {
      int sa = __shfl(srcv, k),     sb = __shfl(srcv, k + 1);
      int sc = __shfl(srcv, k + 2), sd = __shfl(srcv, k + 3);
      unsigned ua = ((const unsigned*)(xwh + (size_t)sa * 128))[lane];
      unsigned ub = ((const unsigned*)(xwh + (size_t)sb * 128))[lane];
      unsigned uc = ((const unsigned*)(xwh + (size_t)sc * 128))[lane];
      unsigned ud = ((const unsigned*)(xwh + (size_t)sd * 128))[lane];
      // convergent: both heads' weights broadcast at full exec, then select
      float w0a = __shfl(w0v, k),     w1a = __shfl(w1v, k);
      float w0b = __shfl(w0v, k + 1), w1b = __shfl(w1v, k + 1);
      float w0c = __shfl(w0v, k + 2), w1c = __shfl(w1v, k + 2);
      float w0d = __shfl(w0v, k + 3), w1d = __shfl(w1v, k + 3);
      float wa = h0 ? w0a : w1a;
      float wb = h0 ? w0b : w1b;
      float wc = h0 ? w0c : w1c;
      float wd = h0 ? w0d : w1d;
      acc.x = fmaf(wa, bflo2f(ua), acc.x); acc.y = fmaf(wa, bfhi2f(ua), acc.y);
      acc.x = fmaf(wb, bflo2f(ub), acc.x); acc.y = fmaf(wb, bfhi2f(ub), acc.y);
      acc.x = fmaf(wc, bflo2f(uc), acc.x); acc.y = fmaf(wc, bfhi2f(uc), acc.y);
      acc.x = fmaf(wd, bflo2f(ud), acc.x); acc.y = fmaf(wd, bfhi2f(ud), acc.y);
    }
    for (; k < cnt; ++k) {
      int s = __shfl(srcv, k);
      float w0b_ = __shfl(w0v, k), w1b_ = __shfl(w1v, k);
      float w = h0 ? w0b_ : w1b_;
      unsigned u = ((const unsigned*)(xwh + (size_t)s * 128))[lane];
      acc.x = fmaf(w, bflo2f(u), acc.x);
      acc.y = fmaf(w, bfhi2f(u), acc.y);
    }
  }
  const float2 bv = ((const float2*)bias)[lane];
  ((unsigned*)(ahc + (size_t)node * 384))[lane] =
      pack2bf(elu1(acc.x + bv.x), elu1(acc.y + bv.y));
}

// ---------------- K6: MFMA MLP: ah[N,384](bf16) @ wc1(bf16) + epilogue ------
// 4 waves/block; wave = 16 rows x 128 cols = 8 acc tiles of 16x16; K=384 in
// 12 steps of 32. A-frags from global (each row read once); B-frags from
// L2-hot pre-swizzled wsw. No LDS, no barriers.
__global__ __launch_bounds__(256) void final_mlp_mfma(
    const unsigned short* __restrict__ ah, const unsigned short* __restrict__ wsw,
    const float* __restrict__ bc1, const float* __restrict__ Wc2,
    const float* __restrict__ bc2, float* __restrict__ out, int Nn) {
  const int tid = threadIdx.x;
  const int l = tid & 63;
  const int w = tid >> 6;
  const int lrow = l & 15;        // A row in tile / D col
  const int lk = (l >> 4) * 8;    // k-offset in 32-chunk
  int row = blockIdx.x * 64 + w * 16 + lrow;
  int arow = row < Nn ? row : Nn - 1;
  const unsigned short* aptr = ah + (size_t)arow * 384 + lk;
  const unsigned short* bptr = wsw + (size_t)l * 8;

  f32x4 acc[8];
#pragma unroll
  for (int n = 0; n < 8; ++n) acc[n] = (f32x4){0.f, 0.f, 0.f, 0.f};

  for (int t = 0; t < 12; ++t) {
    uint4 av = *(const uint4*)(aptr + t * 32);
    short8 af = __builtin_bit_cast(short8, av);
#pragma unroll
    for (int n = 0; n < 8; ++n) {
      uint4 bv = *(const uint4*)(bptr + (size_t)(t * 8 + n) * 512);
      short8 bf = __builtin_bit_cast(short8, bv);
      acc[n] = __builtin_amdgcn_mfma_f32_16x16x32_bf16(af, bf, acc[n], 0, 0, 0);
    }
  }

  // epilogue: h = relu(acc + bc1[col]); out_row = sum_col h*Wc2[col] + bc2
  float bcv[8], w2v[8];
#pragma unroll
  for (int n = 0; n < 8; ++n) {
    int col = n * 16 + lrow;
    bcv[n] = bc1[col];
    w2v[n] = Wc2[col];
  }
  float p[4];
#pragma unroll
  for (int r = 0; r < 4; ++r) {
    float s = 0.f;
#pragma unroll
    for (int n = 0; n < 8; ++n)
      s = fmaf(fmaxf(acc[n][r] + bcv[n], 0.f), w2v[n], s);
#pragma unroll
    for (int off = 1; off < 16; off <<= 1) s += __shfl_xor(s, off);
    p[r] = s;
  }
  if (lrow == 0) {
    int orow = blockIdx.x * 64 + w * 16 + (l >> 4) * 4;
    float b2 = bc2[0];
    if (orow + 3 < Nn) {
      float4 o = {p[0] + b2, p[1] + b2, p[2] + b2, p[3] + b2};
      *(float4*)(out + orow) = o;
    } else {
#pragma unroll
      for (int r = 0; r < 4; ++r)
        if (orow + r < Nn) out[orow + r] = p[r] + b2;
    }
  }
}

// ---------------------------------------------------------------------------
extern "C" void kernel_launch(void* const* d_in, const int* in_sizes, int n_in,
                              void* d_out, int out_size, void* d_ws, size_t ws_size,
                              hipStream_t stream) {
  const int Nn = out_size;            // 40000
  const int E0 = in_sizes[1] / 2;
  const int E1 = in_sizes[7] / 2;
  const int E2 = in_sizes[13] / 2;
  const int totE = E0 + E1 + E2;
  const int Nt = 3 * Nn;
  const int nbpc = (Nn + 127) / 128;  // buckets per category (313)
  const int NB = 3 * nbpc;            // 939

  char* base = (char*)d_ws;
  size_t off = 0;
  auto carve = [&](size_t bytes) -> void* {
    off = (off + 255) & ~(size_t)255;
    void* p = base + off;
    off += bytes;
    return p;
  };
  unsigned short* xwh = (unsigned short*)carve((size_t)Nn * 128 * 2); // bf16
  unsigned short* ah  = (unsigned short*)carve((size_t)Nn * 384 * 2); // bf16 A
  unsigned short* wsw = (unsigned short*)carve((size_t)12 * 8 * 64 * 8 * 2);
  unsigned short* wswx = (unsigned short*)carve((size_t)3 * 4 * 8 * 64 * 8 * 2);
  float* a_src3 = (float*)carve((size_t)Nt * 2 * 4);
  float* a_dst3 = (float*)carve((size_t)Nt * 2 * 4);
  int*  bktCnt  = (int*)carve((size_t)NB * SLICES * 16 * 4); // line-padded
  int2* offcnt3 = (int2*)carve((size_t)Nt * 8);
  int*  bkt     = (int*)carve((size_t)NB * BCAP * 4);
  (void)ws_size; (void)n_in;

  const int* ei0 = (const int*)d_in[1];
  const int* ei1 = (const int*)d_in[7];
  const int* ei2 = (const int*)d_in[13];

  // bucketed adjacency build + one-shot W swizzles
  const int ncnt = NB * SLICES * 16;
  zeroB<<<(ncnt + 255) / 256, 256, 0, stream>>>(bktCnt, ncnt);
  w_swz<<<(12 * 8 * 64 + 255) / 256, 256, 0, stream>>>(
      (const float*)d_in[18], wsw, 12);
  for (int cat = 0; cat < 3; ++cat) {
    const int K = in_sizes[6 * cat] / Nn;
    w_swz<<<((K >> 5) * 8 * 64 + 255) / 256, 256, 0, stream>>>(
        (const float*)d_in[6 * cat + 2], wswx + (size_t)cat * 4 * 8 * 64 * 8,
        K >> 5);
  }
  scatter_p<<<(totE + STB - 1) / STB, SBS, 0, stream>>>(
      ei0, ei1, ei2, E0, E1, E2, nbpc, bktCnt, bkt);
  sortbkt<<<NB, 256, 0, stream>>>(bkt, bktCnt, offcnt3, Nn, nbpc);

  for (int cat = 0; cat < 3; ++cat) {
    const float* x   = (const float*)d_in[6 * cat + 0];
    const float* ats = (const float*)d_in[6 * cat + 3];
    const float* atd = (const float*)d_in[6 * cat + 4];
    const float* bia = (const float*)d_in[6 * cat + 5];
    const int K = in_sizes[6 * cat] / Nn;
    float* a_src_c = a_src3 + (size_t)cat * Nn * 2;
    float* a_dst_c = a_dst3 + (size_t)cat * Nn * 2;

    gemm_att_mfma<<<(Nn + 63) / 64, 256, 0, stream>>>(
        x, wswx + (size_t)cat * 4 * 8 * 64 * 8, ats, atd, xwh,
        a_src_c, a_dst_c, Nn, K);
    aggregate<<<((size_t)Nn * 64 + 255) / 256, 256, 0, stream>>>(
        xwh, a_src_c, a_dst_c, offcnt3 + (size_t)cat * Nn, bkt, bia,
        ah + (size_t)cat * 128, Nn);
  }

  final_mlp_mfma<<<(Nn + 63) / 64, 256, 0, stream>>>(
      ah, wsw, (const float*)d_in[19], (const float*)d_in[20],
      (const float*)d_in[21], (float*)d_out, Nn);
}

// Round 10
// 296.563 us; speedup vs baseline: 1.4505x; 1.0908x over previous
//
#include <hip/hip_runtime.h>
#include <hip/hip_fp16.h>
#include <cstdint>
#include <cstddef>

// ---------------------------------------------------------------------------
// FCAGAT: 3x GATConv (H=2, C=64) + ELU + concat + MLP(384->128->1)
// R8: scatter_p LDS radix-partition. R9/R10: fp32 GEMM dead end (~45% VALU
// eff). R11/R12: __shfl must stay OUT of divergent control flow (inactive-
// source bpermute returns 0 on gfx950); broadcast-then-select. R13: bf16 xw.
// R14/R15: both GEMMs -> MFMA bf16 (layouts harness-verified), 323.5us.
// R16: aggregate restructured 1 node/wave -> 4 nodes/wave (16-lane groups):
// mean degree 16.4 ~= group size, so phase-1 lanes go ~25%->~100% util,
// butterfly 6->4 steps covering 4 nodes at once; phase 2: lane owns 8 cols,
// ONE uint4 load per edge-group step feeds 4 edges, weights fp16x2-packed ->
// 2 shfls per 4 edges (was 12). All shfls full-exec: loop bounds made
// wave-uniform via cross-group shfl_xor max; inactive producer lanes carry
// sv=0/w=0 (row-0 loads cache-absorbed, fma adds exact 0).
//   K1 zeroB        : bktCnt = 0
//   K1b w_swz       : W fp32 -> bf16 MFMA B-fragment order (Wc1 + 3x Wcat)
//   K2 scatter_p    : LDS-partitioned edge scatter -> (bucket,slice) runs
//   K3 sortbkt      : merge slices, LDS counting sort + self-loop inject
//   K4 gemm_att_mfma: xw(bf16) = x@W via MFMA + fused att dots in epilogue
//   K5 aggregate    : 4 nodes/wave softmax + uint4 bf16 gather -> ah elu'd
//   K6 final_mlp_mfma: ah[N,384](bf16) @ Wc1(bf16) MFMA + relu/Wc2 epilogue
// ---------------------------------------------------------------------------

__device__ __forceinline__ float lrelu02(float x) { return x > 0.f ? x : 0.2f * x; }
__device__ __forceinline__ float elu1(float x) { return x > 0.f ? x : (__expf(x) - 1.f); }

// bf16 pack/unpack (RNE; no NaN in this data)
__device__ __forceinline__ unsigned bfrne(float x) {
  unsigned u = __float_as_uint(x);
  return (u + 0x7FFFu + ((u >> 16) & 1u)) >> 16;
}
__device__ __forceinline__ unsigned pack2bf(float lo, float hi) {
  return bfrne(lo) | (bfrne(hi) << 16);
}
__device__ __forceinline__ float bflo2f(unsigned u) { return __uint_as_float(u << 16); }
__device__ __forceinline__ float bfhi2f(unsigned u) { return __uint_as_float(u & 0xFFFF0000u); }

// fp16x2 pack/unpack for shfl'd softmax weights (rel err 2^-11, negligible)
__device__ __forceinline__ unsigned pack2half(float lo, float hi) {
  __half2 h2 = __floats2half2_rn(lo, hi);
  return __builtin_bit_cast(unsigned, h2);
}
__device__ __forceinline__ float h2lo(unsigned u) {
  return __half2float(__low2half(__builtin_bit_cast(__half2, u)));
}
__device__ __forceinline__ float h2hi(unsigned u) {
  return __half2float(__high2half(__builtin_bit_cast(__half2, u)));
}

typedef __attribute__((ext_vector_type(8))) short short8;
typedef __attribute__((ext_vector_type(4))) float f32x4;

#define SLICES 8
#define CAPX 448               // per-(bucket,slice): mean ~240, +13 sigma
#define BCAP (SLICES * CAPX)   // 3584 >= max bucket total (~2046)

#define SBS 512                // scatter block threads
#define SEPT 16                // edges per thread
#define STB (SBS * SEPT)       // 8192 edges per block
#define NBINS_PAD 1024         // >= 3*nbpc = 939, padded pow2

// ---------------- K1: zero (line-padded) bucket counters ----------------
__global__ void zeroB(int* __restrict__ a, int n) {
  int i = blockIdx.x * blockDim.x + threadIdx.x;
  if (i < n) a[i] = 0;
}

// ---------------- K1b: W fp32 -> bf16 MFMA B-fragment order (once) ---------
// frag idx = (t*8+n)*64 + l; elems j=0..7 -> W[t*32 + (l>>4)*8 + j][n*16+(l&15)]
__global__ void w_swz(const float* __restrict__ W,
                      unsigned short* __restrict__ wsw, int nt) {
  int idx = blockIdx.x * blockDim.x + threadIdx.x;
  if (idx >= nt * 8 * 64) return;
  int l = idx & 63;
  int n = (idx >> 6) & 7;
  int t = idx >> 9;
  int col = n * 16 + (l & 15);
  int kbase = t * 32 + (l >> 4) * 8;
  uint4 o;
  o.x = pack2bf(W[(kbase + 0) * 128 + col], W[(kbase + 1) * 128 + col]);
  o.y = pack2bf(W[(kbase + 2) * 128 + col], W[(kbase + 3) * 128 + col]);
  o.z = pack2bf(W[(kbase + 4) * 128 + col], W[(kbase + 5) * 128 + col]);
  o.w = pack2bf(W[(kbase + 6) * 128 + col], W[(kbase + 7) * 128 + col]);
  *(uint4*)(wsw + (size_t)idx * 8) = o;
}

// ---------------- K4: MFMA xw(bf16) = x@W + fused attention dots ------------
// 4 waves/block; wave = 16 rows x 128 cols; K in nt steps of 32. A packed
// fp32->bf16 in-register; B from L2-hot pre-swizzled wsw. No LDS/barriers.
// Layouts (harness-verified in R14): A row=l&15, k=(l>>4)*8+j;
// B k=(l>>4)*8+j, col=n*16+(l&15); D col=l&15, row=(l>>4)*4+r.
__global__ __launch_bounds__(256) void gemm_att_mfma(
    const float* __restrict__ X, const unsigned short* __restrict__ wsw,
    const float* __restrict__ att_s, const float* __restrict__ att_d,
    unsigned short* __restrict__ XWH, float* __restrict__ a_src,
    float* __restrict__ a_dst, int M, int K) {
  const int tid = threadIdx.x;
  const int l = tid & 63;
  const int w = tid >> 6;
  const int lrow = l & 15;
  const int lk = (l >> 4) * 8;
  const int row0 = blockIdx.x * 64 + w * 16;
  int arow = row0 + lrow; if (arow >= M) arow = M - 1;
  const float* aptr = X + (size_t)arow * K + lk;
  const unsigned short* bptr = wsw + (size_t)l * 8;
  const int nt = K >> 5;

  f32x4 acc[8];
#pragma unroll
  for (int n = 0; n < 8; ++n) acc[n] = (f32x4){0.f, 0.f, 0.f, 0.f};

  for (int t = 0; t < nt; ++t) {
    float4 xa = *(const float4*)(aptr + t * 32);
    float4 xb = *(const float4*)(aptr + t * 32 + 4);
    uint4 av;
    av.x = pack2bf(xa.x, xa.y);
    av.y = pack2bf(xa.z, xa.w);
    av.z = pack2bf(xb.x, xb.y);
    av.w = pack2bf(xb.z, xb.w);
    short8 af = __builtin_bit_cast(short8, av);
#pragma unroll
    for (int n = 0; n < 8; ++n) {
      uint4 bv = *(const uint4*)(bptr + (size_t)(t * 8 + n) * 512);
      short8 bf = __builtin_bit_cast(short8, bv);
      acc[n] = __builtin_amdgcn_mfma_f32_16x16x32_bf16(af, bf, acc[n], 0, 0, 0);
    }
  }

  // epilogue: store xw bf16 + attention dots (head0 = n<4, head1 = n>=4)
  float as_[8], ad_[8];
#pragma unroll
  for (int n = 0; n < 8; ++n) {
    int col = n * 16 + lrow;
    as_[n] = att_s[col];
    ad_[n] = att_d[col];
  }
#pragma unroll
  for (int r = 0; r < 4; ++r) {
    int wrow = row0 + (l >> 4) * 4 + r;
    const bool ok = wrow < M;
    float ps0 = 0.f, ps1 = 0.f, pd0 = 0.f, pd1 = 0.f;
#pragma unroll
    for (int n = 0; n < 8; ++n) {
      float v = acc[n][r];
      if (ok) XWH[(size_t)wrow * 128 + n * 16 + lrow] = (unsigned short)bfrne(v);
      if (n < 4) { ps0 = fmaf(v, as_[n], ps0); pd0 = fmaf(v, ad_[n], pd0); }
      else       { ps1 = fmaf(v, as_[n], ps1); pd1 = fmaf(v, ad_[n], pd1); }
    }
    // convergent 16-lane reduce (full exec; stores above are predicated only)
#pragma unroll
    for (int off = 1; off < 16; off <<= 1) {
      ps0 += __shfl_xor(ps0, off); ps1 += __shfl_xor(ps1, off);
      pd0 += __shfl_xor(pd0, off); pd1 += __shfl_xor(pd1, off);
    }
    if (lrow == 0 && ok) {
      ((float2*)a_src)[wrow] = make_float2(ps0, ps1);
      ((float2*)a_dst)[wrow] = make_float2(pd0, pd1);
    }
  }
}

// ---------------- K2: LDS radix-partition edge scatter ----------------
__global__ __launch_bounds__(512) void scatter_p(
    const int* __restrict__ ei0, const int* __restrict__ ei1,
    const int* __restrict__ ei2, int E0, int E1, int E2,
    int nbpc, int* __restrict__ bktCnt, int* __restrict__ bkt) {
  __shared__ int hist[NBINS_PAD];
  __shared__ int binStart[NBINS_PAD];
  __shared__ int binResv[NBINS_PAD];
  __shared__ int fillB[NBINS_PAD];
  __shared__ int scanBuf[SBS];
  __shared__ int stage[STB];
  __shared__ int gdst[STB];
  const int tid = threadIdx.x;
  const int slice = blockIdx.x & (SLICES - 1);   // ~= XCD id (round-robin)
  const int nbins = 3 * nbpc;
  const int c1 = E0, c2 = E0 + E1, totE = c2 + E2;
  const int eb = blockIdx.x * STB;

  for (int b = tid; b < NBINS_PAD; b += SBS) hist[b] = 0;
  __syncthreads();

  // load 16 edges/thread, histogram bins
  int binv[SEPT], payv[SEPT];
#pragma unroll
  for (int k = 0; k < SEPT; ++k) {
    int g = eb + k * SBS + tid;
    int bn = -1, pay = 0;
    if (g < totE) {
      int s, d, cat;
      if (g < c1)      { s = ei0[g]; d = ei0[E0 + g]; cat = 0; }
      else if (g < c2) { int t = g - c1; s = ei1[t]; d = ei1[E1 + t]; cat = 1; }
      else             { int t = g - c2; s = ei2[t]; d = ei2[E2 + t]; cat = 2; }
      bn = cat * nbpc + (d >> 7);
      pay = ((d & 127) << 16) | s;
      atomicAdd(&hist[bn], 1);
    }
    binv[k] = bn; payv[k] = pay;
  }
  __syncthreads();

  // exclusive scan of hist -> binStart (2 bins/thread, Hillis-Steele on 512)
  const int a0 = hist[tid * 2], a1 = hist[tid * 2 + 1];
  scanBuf[tid] = a0 + a1;
  __syncthreads();
  for (int off = 1; off < SBS; off <<= 1) {
    int v = (tid >= off) ? scanBuf[tid - off] : 0;
    __syncthreads();
    scanBuf[tid] += v;
    __syncthreads();
  }
  const int total = scanBuf[SBS - 1];
  const int base = (tid > 0) ? scanBuf[tid - 1] : 0;
  binStart[tid * 2] = base;
  binStart[tid * 2 + 1] = base + a0;

  // reserve a contiguous run per non-empty bin (XCD-private slice counters)
  for (int b = tid; b < NBINS_PAD; b += SBS) {
    fillB[b] = 0;
    int c = hist[b];
    if (c > 0 && b < nbins)
      binResv[b] = atomicAdd(&bktCnt[(b * SLICES + slice) * 16], c);
  }
  __syncthreads();

  // counting-sort edges into LDS stage, record global destination
#pragma unroll
  for (int k = 0; k < SEPT; ++k) {
    int bn = binv[k];
    if (bn >= 0) {
      int f = atomicAdd(&fillB[bn], 1);
      int p = binStart[bn] + f;
      int go = binResv[bn] + f;
      stage[p] = payv[k];
      gdst[p] = (go < CAPX) ? ((bn * SLICES + slice) * CAPX + go) : -1;
    }
  }
  __syncthreads();

  // run-ordered write-out: consecutive lanes -> consecutive addresses
  for (int i = tid; i < total; i += SBS) {
    int g = gdst[i];
    if (g >= 0) bkt[g] = stage[i];
  }
}

// ---------------- K3: merge slices, LDS counting sort, compact in place -----
// Self-loops injected analytically: cntA init = 1, self-loop src at slot
// scanA[t]-1 (edges fill relative slots 0..cntA-2 via fillA).
__global__ __launch_bounds__(256) void sortbkt(
    int* __restrict__ bkt, const int* __restrict__ bktCnt,
    int2* __restrict__ offcnt, int Nn, int nbpc) {
  __shared__ int cntA[128], scanA[128], fillA[128];
  __shared__ int esort[BCAP];
  const int tid = threadIdx.x;
  const int b = blockIdx.x;
  const int cat = b / nbpc, bl = b - cat * nbpc, dBase = bl << 7;
  if (tid < 128) {
    cntA[tid] = (dBase + tid < Nn) ? 1 : 0;   // self-loop
    fillA[tid] = 0;
  }
  __syncthreads();
  int ns[SLICES];
#pragma unroll
  for (int s = 0; s < SLICES; ++s)
    ns[s] = min(bktCnt[(b * SLICES + s) * 16], CAPX);
  // pass 1: histogram by dLow
#pragma unroll
  for (int s = 0; s < SLICES; ++s) {
    const int* seg = bkt + (size_t)(b * SLICES + s) * CAPX;
    for (int i = tid; i < ns[s]; i += 256) atomicAdd(&cntA[seg[i] >> 16], 1);
  }
  __syncthreads();
  if (tid < 128) scanA[tid] = cntA[tid];
  __syncthreads();
  for (int off = 1; off < 128; off <<= 1) {
    int t = (tid < 128 && tid >= off) ? scanA[tid - off] : 0;
    __syncthreads();
    if (tid < 128) scanA[tid] += t;
    __syncthreads();
  }
  // pass 2: place edges (exclusive start for node t = scanA[t]-cntA[t])
#pragma unroll
  for (int s = 0; s < SLICES; ++s) {
    const int* seg = bkt + (size_t)(b * SLICES + s) * CAPX;
    for (int i = tid; i < ns[s]; i += 256) {
      int v = seg[i];
      int n = v >> 16;
      int p = scanA[n] - cntA[n] + atomicAdd(&fillA[n], 1);
      esort[p] = v & 0xFFFF;
    }
  }
  // self-loop: last slot of node's segment
  if (tid < 128 && dBase + tid < Nn) esort[scanA[tid] - 1] = dBase + tid;
  __syncthreads();
  const int tot = scanA[127];
  int* outp = bkt + (size_t)b * BCAP;     // compact to bucket base
  for (int i = tid; i < tot; i += 256) outp[i] = esort[i];
  if (tid < 128 && dBase + tid < Nn)
    offcnt[(size_t)cat * Nn + dBase + tid] =
        make_int2(b * BCAP + scanA[tid] - cntA[tid], cntA[tid]);
}

// ---------------- K5: 4 nodes/wave softmax + uint4 bf16 gather --------------
// Group g = lanes 16g..16g+15 owns node wid*4+g; lane li=lane&15 owns cols
// [li*8, li*8+8). Phase 1: group-strided stats (no shfl inside divergent
// loop); 4-step butterfly reduces all 4 nodes at once. Phase 2: per chunk,
// lane li's edge -> (sv, fp16x2-packed weights); inner loop bounds made
// WAVE-UNIFORM via cross-group shfl_xor max so every __shfl runs at full
// exec (R11 rule); inactive producers carry sv=0/w=0 (exp(-inf)=0).
__global__ __launch_bounds__(256) void aggregate(
    const unsigned short* __restrict__ xwh, const float* __restrict__ a_src,
    const float* __restrict__ a_dst, const int2* __restrict__ offcnt,
    const int* __restrict__ adjS, const float* __restrict__ bias,
    unsigned short* __restrict__ ahc, int Nn) {
  const int tid = threadIdx.x;
  const int lane = tid & 63;
  const int li = lane & 15;          // lane in group
  const int gb = lane & 48;          // group base lane
  const int wid = (int)((blockIdx.x * (size_t)blockDim.x + tid) >> 6);
  const int node = wid * 4 + (lane >> 4);
  const bool nok = node < Nn;
  const int cnode = nok ? node : Nn - 1;
  const int2 oc = offcnt[cnode];
  const int base = oc.x;
  const int cnt = oc.y;              // >= 1 (self-loop)
  const float2 ad = ((const float2*)a_dst)[cnode];

  // phase 1: group-strided online softmax stats; keep first chunk in regs
  float m0 = -1e30f, s0 = 0.f, m1 = -1e30f, s1 = 0.f;
  int sv0 = 0; float ex0 = -1e30f, ey0 = -1e30f;
  for (int cb = 0; cb < cnt; cb += 16) {
    int sv = 0; float ex = -1e30f, ey = -1e30f;
    if (cb + li < cnt) {
      sv = adjS[base + cb + li];
      float2 as = ((const float2*)a_src)[sv];
      ex = lrelu02(as.x + ad.x);
      ey = lrelu02(as.y + ad.y);
      float nm0 = fmaxf(m0, ex);
      s0 = s0 * __expf(m0 - nm0) + __expf(ex - nm0); m0 = nm0;
      float nm1 = fmaxf(m1, ey);
      s1 = s1 * __expf(m1 - nm1) + __expf(ey - nm1); m1 = nm1;
    }
    if (cb == 0) { sv0 = sv; ex0 = ex; ey0 = ey; }
  }
  // 16-lane butterfly (xor<16 stays in group), convergent full-exec
#pragma unroll
  for (int off = 8; off; off >>= 1) {
    float om0 = __shfl_xor(m0, off), os0 = __shfl_xor(s0, off);
    float nm0 = fmaxf(m0, om0);
    s0 = s0 * __expf(m0 - nm0) + os0 * __expf(om0 - nm0); m0 = nm0;
    float om1 = __shfl_xor(m1, off), os1 = __shfl_xor(s1, off);
    float nm1 = fmaxf(m1, om1);
    s1 = s1 * __expf(m1 - nm1) + os1 * __expf(om1 - nm1); m1 = nm1;
  }
  const float inv0 = 1.f / s0, inv1 = 1.f / s1;

  // wave-uniform outer bound: max cnt over the wave's 4 groups
  int mc = cnt;
  mc = max(mc, __shfl_xor(mc, 16));
  mc = max(mc, __shfl_xor(mc, 32));

  const bool hlo = (li < 8);   // cols < 64 -> head0
  float acc[8];
#pragma unroll
  for (int c = 0; c < 8; ++c) acc[c] = 0.f;

  for (int cb = 0; cb < mc; cb += 16) {
    // per-lane edge (cb+li) of its group: srcv + packed fp16 weights
    int sv; float ex, ey;
    if (cb == 0) { sv = sv0; ex = ex0; ey = ey0; }
    else {
      sv = 0; ex = -1e30f; ey = -1e30f;
      if (cb + li < cnt) {
        sv = adjS[base + cb + li];
        float2 as = ((const float2*)a_src)[sv];
        ex = lrelu02(as.x + ad.x);
        ey = lrelu02(as.y + ad.y);
      }
    }
    const float w0 = __expf(ex - m0) * inv0;   // inactive lanes -> 0
    const float w1 = __expf(ey - m1) * inv1;
    const unsigned wpk = pack2half(w0, w1);

    // wave-uniform inner bound: max chunk count over groups
    int cc = cnt - cb; cc = cc < 0 ? 0 : (cc > 16 ? 16 : cc);
    cc = max(cc, __shfl_xor(cc, 16));
    cc = max(cc, __shfl_xor(cc, 32));

    int k = 0;
    for (; k + 2 <= cc; k += 2) {
      int ska = __shfl(sv, gb + k);            // full exec
      int skb = __shfl(sv, gb + k + 1);
      unsigned wka = __shfl(wpk, gb + k);
      unsigned wkb = __shfl(wpk, gb + k + 1);
      uint4 ua = *(const uint4*)(xwh + (size_t)ska * 128 + li * 8);
      uint4 ub = *(const uint4*)(xwh + (size_t)skb * 128 + li * 8);
      float wa = hlo ? h2lo(wka) : h2hi(wka);  // select AFTER shfl
      float wb = hlo ? h2lo(wkb) : h2hi(wkb);
      acc[0] = fmaf(wa, bflo2f(ua.x), acc[0]); acc[1] = fmaf(wa, bfhi2f(ua.x), acc[1]);
      acc[2] = fmaf(wa, bflo2f(ua.y), acc[2]); acc[3] = fmaf(wa, bfhi2f(ua.y), acc[3]);
      acc[4] = fmaf(wa, bflo2f(ua.z), acc[4]); acc[5] = fmaf(wa, bfhi2f(ua.z), acc[5]);
      acc[6] = fmaf(wa, bflo2f(ua.w), acc[6]); acc[7] = fmaf(wa, bfhi2f(ua.w), acc[7]);
      acc[0] = fmaf(wb, bflo2f(ub.x), acc[0]); acc[1] = fmaf(wb, bfhi2f(ub.x), acc[1]);
      acc[2] = fmaf(wb, bflo2f(ub.y), acc[2]); acc[3] = fmaf(wb, bfhi2f(ub.y), acc[3]);
      acc[4] = fmaf(wb, bflo2f(ub.z), acc[4]); acc[5] = fmaf(wb, bfhi2f(ub.z), acc[5]);
      acc[6] = fmaf(wb, bflo2f(ub.w), acc[6]); acc[7] = fmaf(wb, bfhi2f(ub.w), acc[7]);
    }
    for (; k < cc; ++k) {
      int sk = __shfl(sv, gb + k);
      unsigned wk = __shfl(wpk, gb + k);
      float w = hlo ? h2lo(wk) : h2hi(wk);
      uint4 u = *(const uint4*)(xwh + (size_t)sk * 128 + li * 8);
      acc[0] = fmaf(w, bflo2f(u.x), acc[0]); acc[1] = fmaf(w, bfhi2f(u.x), acc[1]);
      acc[2] = fmaf(w, bflo2f(u.y), acc[2]); acc[3] = fmaf(w, bfhi2f(u.y), acc[3]);
      acc[4] = fmaf(w, bflo2f(u.z), acc[4]); acc[5] = fmaf(w, bfhi2f(u.z), acc[5]);
      acc[6] = fmaf(w, bflo2f(u.w), acc[6]); acc[7] = fmaf(w, bfhi2f(u.w), acc[7]);
    }
  }

  // store: cols [li*8, li*8+8) of this cat's 128-block; elu+bias fused
  if (nok) {
    const float4 b0 = *(const float4*)(bias + li * 8);
    const float4 b1 = *(const float4*)(bias + li * 8 + 4);
    uint4 o;
    o.x = pack2bf(elu1(acc[0] + b0.x), elu1(acc[1] + b0.y));
    o.y = pack2bf(elu1(acc[2] + b0.z), elu1(acc[3] + b0.w));
    o.z = pack2bf(elu1(acc[4] + b1.x), elu1(acc[5] + b1.y));
    o.w = pack2bf(elu1(acc[6] + b1.z), elu1(acc[7] + b1.w));
    *(uint4*)(ahc + (size_t)node * 384 + li * 8) = o;
  }
}

// ---------------- K6: MFMA MLP: ah[N,384](bf16) @ wc1(bf16) + epilogue ------
// 4 waves/block; wave = 16 rows x 128 cols = 8 acc tiles of 16x16; K=384 in
// 12 steps of 32. A-frags from global (each row read once); B-frags from
// L2-hot pre-swizzled wsw. No LDS, no barriers.
__global__ __launch_bounds__(256) void final_mlp_mfma(
    const unsigned short* __restrict__ ah, const unsigned short* __restrict__ wsw,
    const float* __restrict__ bc1, const float* __restrict__ Wc2,
    const float* __restrict__ bc2, float* __restrict__ out, int Nn) {
  const int tid = threadIdx.x;
  const int l = tid & 63;
  const int w = tid >> 6;
  const int lrow = l & 15;        // A row in tile / D col
  const int lk = (l >> 4) * 8;    // k-offset in 32-chunk
  int row = blockIdx.x * 64 + w * 16 + lrow;
  int arow = row < Nn ? row : Nn - 1;
  const unsigned short* aptr = ah + (size_t)arow * 384 + lk;
  const unsigned short* bptr = wsw + (size_t)l * 8;

  f32x4 acc[8];
#pragma unroll
  for (int n = 0; n < 8; ++n) acc[n] = (f32x4){0.f, 0.f, 0.f, 0.f};

  for (int t = 0; t < 12; ++t) {
    uint4 av = *(const uint4*)(aptr + t * 32);
    short8 af = __builtin_bit_cast(short8, av);
#pragma unroll
    for (int n = 0; n < 8; ++n) {
      uint4 bv = *(const uint4*)(bptr + (size_t)(t * 8 + n) * 512);
      short8 bf = __builtin_bit_cast(short8, bv);
      acc[n] = __builtin_amdgcn_mfma_f32_16x16x32_bf16(af, bf, acc[n], 0, 0, 0);
    }
  }

  // epilogue: h = relu(acc + bc1[col]); out_row = sum_col h*Wc2[col] + bc2
  float bcv[8], w2v[8];
#pragma unroll
  for (int n = 0; n < 8; ++n) {
    int col = n * 16 + lrow;
    bcv[n] = bc1[col];
    w2v[n] = Wc2[col];
  }
  float p[4];
#pragma unroll
  for (int r = 0; r < 4; ++r) {
    float s = 0.f;
#pragma unroll
    for (int n = 0; n < 8; ++n)
      s = fmaf(fmaxf(acc[n][r] + bcv[n], 0.f), w2v[n], s);
#pragma unroll
    for (int off = 1; off < 16; off <<= 1) s += __shfl_xor(s, off);
    p[r] = s;
  }
  if (lrow == 0) {
    int orow = blockIdx.x * 64 + w * 16 + (l >> 4) * 4;
    float b2 = bc2[0];
    if (orow + 3 < Nn) {
      float4 o = {p[0] + b2, p[1] + b2, p[2] + b2, p[3] + b2};
      *(float4*)(out + orow) = o;
    } else {
#pragma unroll
      for (int r = 0; r < 4; ++r)
        if (orow + r < Nn) out[orow + r] = p[r] + b2;
    }
  }
}

// ---------------------------------------------------------------------------
extern "C" void kernel_launch(void* const* d_in, const int* in_sizes, int n_in,
                              void* d_out, int out_size, void* d_ws, size_t ws_size,
                              hipStream_t stream) {
  const int Nn = out_size;            // 40000
  const int E0 = in_sizes[1] / 2;
  const int E1 = in_sizes[7] / 2;
  const int E2 = in_sizes[13] / 2;
  const int totE = E0 + E1 + E2;
  const int Nt = 3 * Nn;
  const int nbpc = (Nn + 127) / 128;  // buckets per category (313)
  const int NB = 3 * nbpc;            // 939

  char* base = (char*)d_ws;
  size_t off = 0;
  auto carve = [&](size_t bytes) -> void* {
    off = (off + 255) & ~(size_t)255;
    void* p = base + off;
    off += bytes;
    return p;
  };
  unsigned short* xwh = (unsigned short*)carve((size_t)Nn * 128 * 2); // bf16
  unsigned short* ah  = (unsigned short*)carve((size_t)Nn * 384 * 2); // bf16 A
  unsigned short* wsw = (unsigned short*)carve((size_t)12 * 8 * 64 * 8 * 2);
  unsigned short* wswx = (unsigned short*)carve((size_t)3 * 4 * 8 * 64 * 8 * 2);
  float* a_src3 = (float*)carve((size_t)Nt * 2 * 4);
  float* a_dst3 = (float*)carve((size_t)Nt * 2 * 4);
  int*  bktCnt  = (int*)carve((size_t)NB * SLICES * 16 * 4); // line-padded
  int2* offcnt3 = (int2*)carve((size_t)Nt * 8);
  int*  bkt     = (int*)carve((size_t)NB * BCAP * 4);
  (void)ws_size; (void)n_in;

  const int* ei0 = (const int*)d_in[1];
  const int* ei1 = (const int*)d_in[7];
  const int* ei2 = (const int*)d_in[13];

  // bucketed adjacency build + one-shot W swizzles
  const int ncnt = NB * SLICES * 16;
  zeroB<<<(ncnt + 255) / 256, 256, 0, stream>>>(bktCnt, ncnt);
  w_swz<<<(12 * 8 * 64 + 255) / 256, 256, 0, stream>>>(
      (const float*)d_in[18], wsw, 12);
  for (int cat = 0; cat < 3; ++cat) {
    const int K = in_sizes[6 * cat] / Nn;
    w_swz<<<((K >> 5) * 8 * 64 + 255) / 256, 256, 0, stream>>>(
        (const float*)d_in[6 * cat + 2], wswx + (size_t)cat * 4 * 8 * 64 * 8,
        K >> 5);
  }
  scatter_p<<<(totE + STB - 1) / STB, SBS, 0, stream>>>(
      ei0, ei1, ei2, E0, E1, E2, nbpc, bktCnt, bkt);
  sortbkt<<<NB, 256, 0, stream>>>(bkt, bktCnt, offcnt3, Nn, nbpc);

  for (int cat = 0; cat < 3; ++cat) {
    const float* x   = (const float*)d_in[6 * cat + 0];
    const float* ats = (const float*)d_in[6 * cat + 3];
    const float* atd = (const float*)d_in[6 * cat + 4];
    const float* bia = (const float*)d_in[6 * cat + 5];
    const int K = in_sizes[6 * cat] / Nn;
    float* a_src_c = a_src3 + (size_t)cat * Nn * 2;
    float* a_dst_c = a_dst3 + (size_t)cat * Nn * 2;

    gemm_att_mfma<<<(Nn + 63) / 64, 256, 0, stream>>>(
        x, wswx + (size_t)cat * 4 * 8 * 64 * 8, ats, atd, xwh,
        a_src_c, a_dst_c, Nn, K);
    aggregate<<<(Nn + 15) / 16, 256, 0, stream>>>(
        xwh, a_src_c, a_dst_c, offcnt3 + (size_t)cat * Nn, bkt, bia,
        ah + (size_t)cat * 128, Nn);
  }

  final_mlp_mfma<<<(Nn + 63) / 64, 256, 0, stream>>>(
      ah, wsw, (const float*)d_in[19], (const float*)d_in[20],
      (const float*)d_in[21], (float*)d_out, Nn);
}